// Round 1
// baseline (1010.205 us; speedup 1.0000x reference)
//
#include <hip/hip_runtime.h>
#include <hip/hip_bf16.h>
#include <stdint.h>

#define NN 50000
#define NE 800000

using bf16 = __hip_bfloat16;

// ---------- dtype helpers ----------
__device__ __forceinline__ float bf2f_bits(unsigned short u) {
  unsigned int x = ((unsigned int)u) << 16;
  float f;
  __builtin_memcpy(&f, &x, 4);
  return f;
}
__device__ __forceinline__ unsigned short f2bf_bits(float f) {
  unsigned int x;
  __builtin_memcpy(&x, &f, 4);
  unsigned int lsb = (x >> 16) & 1u;
  x += 0x7fffu + lsb;                       // round to nearest even
  return (unsigned short)(x >> 16);
}
__device__ __forceinline__ float loadf(const void* base, size_t idx, int isbf) {
  if (isbf) return bf2f_bits(((const unsigned short*)base)[idx]);
  return ((const float*)base)[idx];
}

// ---------- dtype sniffing (deterministic, graph-safe) ----------
// flags[0]=1 -> float tensors are bf16 on device, else fp32
// flags[1]=1 -> edge_index is int64 on device, else int32
__global__ void k_sniff(const void* x, const void* ei, int* flags) {
  __shared__ int badbf;
  __shared__ int zodd;
  int tid = threadIdx.x;
  if (tid == 0) { badbf = 0; zodd = 0; }
  __syncthreads();
  unsigned short u = ((const unsigned short*)x)[tid];
  float v = bf2f_bits(u);
  float av = fabsf(v);
  int ok = (av == 0.0f) || (av > 1e-8f && av < 1e8f);
  if (!ok) atomicAdd(&badbf, 1);
  int e32 = ((const int*)ei)[tid];
  if ((tid & 1) && e32 == 0) atomicAdd(&zodd, 1);
  __syncthreads();
  if (tid == 0) {
    flags[0] = (badbf <= 12) ? 1 : 0;   // genuine bf16 data: ~0 bad; fp32 read as bf16: ~100 bad
    flags[1] = (zodd >= 100) ? 1 : 0;   // int64 (<2^31 values): all 128 odd words zero
  }
}

__global__ void k_cvt_edges(const void* ei, int* erow, int* ecol, const int* flags) {
  int e = blockIdx.x * 256 + threadIdx.x;
  if (e >= NE) return;
  if (flags[1]) {
    const long long* p = (const long long*)ei;
    erow[e] = (int)p[e];
    ecol[e] = (int)p[NE + e];
  } else {
    const int* p = (const int*)ei;
    erow[e] = p[e];
    ecol[e] = p[NE + e];
  }
}

__global__ void k_cvt_x(const void* x, float* xf, const int* flags) {
  int i = blockIdx.x * 256 + threadIdx.x;
  if (i < NN * 128) xf[i] = loadf(x, (size_t)i, flags[0]);
}

// ---------- degree / CSR ----------
__global__ void k_zero_int(int* p, int n) {
  int i = blockIdx.x * 256 + threadIdx.x;
  if (i < n) p[i] = 0;
}
__global__ void k_count(const int* ecol, int* cnt) {
  int e = blockIdx.x * 256 + threadIdx.x;
  if (e < NE) atomicAdd(&cnt[ecol[e]], 1);
}
__global__ void k_dinv(const int* cnt, float* dinv) {
  int i = blockIdx.x * 256 + threadIdx.x;
  if (i < NN) dinv[i] = rsqrtf((float)(cnt[i] + 1));   // +1 self loop
}
__global__ void k_scan1(const int* cnt, int* indptr, int* bsum, int n) {
  __shared__ int sm[256];
  int tid = threadIdx.x;
  int i = blockIdx.x * 256 + tid;
  int v = (i < n) ? cnt[i] : 0;
  sm[tid] = v;
  __syncthreads();
  for (int off = 1; off < 256; off <<= 1) {
    int t = (tid >= off) ? sm[tid - off] : 0;
    __syncthreads();
    sm[tid] += t;
    __syncthreads();
  }
  if (i < n) indptr[i] = sm[tid] - v;          // local exclusive
  if (tid == 255) bsum[blockIdx.x] = sm[255];  // block total
}
__global__ void k_scan2(int* bsum, int nb) {
  __shared__ int sm[256];
  int tid = threadIdx.x;
  int v = (tid < nb) ? bsum[tid] : 0;
  sm[tid] = v;
  __syncthreads();
  for (int off = 1; off < 256; off <<= 1) {
    int t = (tid >= off) ? sm[tid - off] : 0;
    __syncthreads();
    sm[tid] += t;
    __syncthreads();
  }
  if (tid < nb) bsum[tid] = sm[tid] - v;       // exclusive block offsets
  if (tid == 0) bsum[nb] = sm[255];            // grand total
}
__global__ void k_scan3(int* indptr, const int* bsum, int n, int nb) {
  int i = blockIdx.x * 256 + threadIdx.x;
  if (i < n) indptr[i] += bsum[i >> 8];
  else if (i == n) indptr[n] = bsum[nb];
}
__global__ void k_fill(const int* erow, const int* ecol, const int* indptr,
                       int* fill, int* srcs) {
  int e = blockIdx.x * 256 + threadIdx.x;
  if (e >= NE) return;
  int c = ecol[e];
  int p = indptr[c] + atomicAdd(&fill[c], 1);
  srcs[p] = erow[e];
}

// ---------- BN folding:  bn(h)@W = h@W' + c ----------
__global__ void k_prep_w(const void* W, const void* g, const void* rv,
                         float* Wp, int K, int NOUT, const int* flags) {
  int idx = blockIdx.x * 256 + threadIdx.x;
  if (idx >= K * NOUT) return;
  int isbf = flags[0];
  int k = idx / NOUT;
  float s = loadf(g, k, isbf) * rsqrtf(loadf(rv, k, isbf) + 1e-5f);
  Wp[idx] = s * loadf(W, (size_t)idx, isbf);
}
__global__ void k_prep_c(const void* W, const void* g, const void* b,
                         const void* rm, const void* rv, float* cvec,
                         int K, int NOUT, const int* flags) {
  int j = threadIdx.x;
  if (j >= NOUT) return;
  int isbf = flags[0];
  float acc = 0.f;
  for (int k = 0; k < K; ++k) {
    float s = loadf(g, k, isbf) * rsqrtf(loadf(rv, k, isbf) + 1e-5f);
    float t = loadf(b, k, isbf) - loadf(rm, k, isbf) * s;
    acc += t * loadf(W, (size_t)k * NOUT + j, isbf);
  }
  cvec[j] = acc;
}

// ---------- GEMM: hws[i][j] = dinv[i] * ( h[i,:] @ Wp[:,j] + c[j] ) ----------
// h regions are fp32 [NN][128] each (K/128 regions). 64-row tiles, Kc=64 chunks.
template <int NOUT>
__global__ __launch_bounds__(256) void k_gemm(
    const float* __restrict__ h0, const float* __restrict__ h1,
    const float* __restrict__ h2, const float* __restrict__ Wp,
    const float* __restrict__ cvec, const float* __restrict__ dinv,
    float* __restrict__ hws, int K) {
  constexpr int NCQ = NOUT / 8;   // col groups of 8
  constexpr int NRQ = 256 / NCQ;  // row groups
  constexpr int RPT = 64 / NRQ;   // rows per thread
  __shared__ float h_lds[64][65];       // +1 pad: rq reads conflict-free
  __shared__ float w_lds[64][NOUT];
  int tid = threadIdx.x;
  int row0 = blockIdx.x * 64;
  int rq = tid % NRQ;             // lanes 0..NRQ-1 share cq -> w broadcast
  int cq = tid / NRQ;
  float acc[RPT][8];
#pragma unroll
  for (int r = 0; r < RPT; ++r)
#pragma unroll
    for (int c = 0; c < 8; ++c) acc[r][c] = 0.f;

  for (int k0 = 0; k0 < K; k0 += 64) {
    // stage W chunk (64 x NOUT fp32), coalesced float4
    {
      const float* wsrc = Wp + (size_t)k0 * NOUT;
      constexpr int TOT4 = 64 * NOUT / 4;
      for (int u = tid; u < TOT4; u += 256) {
        float4 v = *reinterpret_cast<const float4*>(wsrc + (size_t)u * 4);
        int kk = (u * 4) / NOUT, cc = (u * 4) % NOUT;
        *reinterpret_cast<float4*>(&w_lds[kk][cc]) = v;
      }
    }
    // stage h chunk (64 rows x 64 k-cols); chunk never straddles a 128-region
    {
      int rg = k0 >> 7;
      int ko = k0 & 127;
      const float* fsrc = (rg == 0) ? h0 : ((rg == 1) ? h1 : h2);
      for (int u = tid; u < 64 * 16; u += 256) {
        int r = u >> 4, c4 = (u & 15) * 4;
        int grow = row0 + r;
        float v0 = 0.f, v1 = 0.f, v2 = 0.f, v3 = 0.f;
        if (grow < NN) {
          float4 v = *reinterpret_cast<const float4*>(fsrc + (size_t)grow * 128 + ko + c4);
          v0 = v.x; v1 = v.y; v2 = v.z; v3 = v.w;
        }
        h_lds[r][c4 + 0] = v0; h_lds[r][c4 + 1] = v1;
        h_lds[r][c4 + 2] = v2; h_lds[r][c4 + 3] = v3;
      }
    }
    __syncthreads();
#pragma unroll 4
    for (int kk = 0; kk < 64; ++kk) {
      float a[RPT];
#pragma unroll
      for (int r = 0; r < RPT; ++r) a[r] = h_lds[rq * RPT + r][kk];
      float4 w0 = *reinterpret_cast<const float4*>(&w_lds[kk][cq * 8]);
      float4 w1 = *reinterpret_cast<const float4*>(&w_lds[kk][cq * 8 + 4]);
#pragma unroll
      for (int r = 0; r < RPT; ++r) {
        acc[r][0] += a[r] * w0.x; acc[r][1] += a[r] * w0.y;
        acc[r][2] += a[r] * w0.z; acc[r][3] += a[r] * w0.w;
        acc[r][4] += a[r] * w1.x; acc[r][5] += a[r] * w1.y;
        acc[r][6] += a[r] * w1.z; acc[r][7] += a[r] * w1.w;
      }
    }
    __syncthreads();
  }
  float4 cv0 = *reinterpret_cast<const float4*>(cvec + cq * 8);
  float4 cv1 = *reinterpret_cast<const float4*>(cvec + cq * 8 + 4);
#pragma unroll
  for (int r = 0; r < RPT; ++r) {
    int grow = row0 + rq * RPT + r;
    if (grow >= NN) continue;
    float dv = dinv[grow];
    float4 o0, o1;
    o0.x = dv * (acc[r][0] + cv0.x); o0.y = dv * (acc[r][1] + cv0.y);
    o0.z = dv * (acc[r][2] + cv0.z); o0.w = dv * (acc[r][3] + cv0.w);
    o1.x = dv * (acc[r][4] + cv1.x); o1.y = dv * (acc[r][5] + cv1.y);
    o1.z = dv * (acc[r][6] + cv1.z); o1.w = dv * (acc[r][7] + cv1.w);
    float* dst = hws + (size_t)grow * NOUT + cq * 8;
    *reinterpret_cast<float4*>(dst) = o0;
    *reinterpret_cast<float4*>(dst + 4) = o1;
  }
}

// ---------- aggregation: one wave per node, gather from CSR ----------
template <int DPL, bool RELU>
__global__ __launch_bounds__(256) void k_agg(
    const float* __restrict__ hws, const int* __restrict__ indptr,
    const int* __restrict__ srcs, const float* __restrict__ dinv,
    const void* __restrict__ bias, void* __restrict__ dout, size_t region_off,
    float* __restrict__ outf, const int* __restrict__ flags) {
  constexpr int NOUT = DPL * 64;
  int gw = (blockIdx.x * 256 + threadIdx.x) >> 6;
  int lane = threadIdx.x & 63;
  if (gw >= NN) return;
  int isbf = flags[0];
  float acc0[DPL], acc1[DPL];
  const float* self = hws + (size_t)gw * NOUT + lane * DPL;
#pragma unroll
  for (int d = 0; d < DPL; ++d) { acc0[d] = self[d]; acc1[d] = 0.f; }
  int e0 = indptr[gw], e1 = indptr[gw + 1];
  int e = e0;
  for (; e + 1 < e1; e += 2) {   // 2-edge unroll for memory-level parallelism
    int s0 = srcs[e], s1 = srcs[e + 1];
    const float* p0 = hws + (size_t)s0 * NOUT + lane * DPL;
    const float* p1 = hws + (size_t)s1 * NOUT + lane * DPL;
    if constexpr (DPL == 2) {
      float2 v0 = *reinterpret_cast<const float2*>(p0);
      float2 v1 = *reinterpret_cast<const float2*>(p1);
      acc0[0] += v0.x; acc0[1] += v0.y;
      acc1[0] += v1.x; acc1[1] += v1.y;
    } else {
      acc0[0] += p0[0];
      acc1[0] += p1[0];
    }
  }
  if (e < e1) {
    int s0 = srcs[e];
    const float* p0 = hws + (size_t)s0 * NOUT + lane * DPL;
    if constexpr (DPL == 2) {
      float2 v0 = *reinterpret_cast<const float2*>(p0);
      acc0[0] += v0.x; acc0[1] += v0.y;
    } else {
      acc0[0] += p0[0];
    }
  }
  float dv = dinv[gw];
#pragma unroll
  for (int d = 0; d < DPL; ++d) {
    float o = dv * (acc0[d] + acc1[d]) + loadf(bias, (size_t)(lane * DPL + d), isbf);
    if (RELU) o = fmaxf(o, 0.f);
    size_t eo = region_off + (size_t)gw * NOUT + lane * DPL + d;
    if (isbf) ((unsigned short*)dout)[eo] = f2bf_bits(o);
    else      ((float*)dout)[eo] = o;
    if (outf) outf[(size_t)gw * NOUT + lane * DPL + d] = o;
  }
}

extern "C" void kernel_launch(void* const* d_in, const int* in_sizes, int n_in,
                              void* d_out, int out_size, void* d_ws, size_t ws_size,
                              hipStream_t stream) {
  const void* x    = d_in[0];
  const void* ei   = d_in[1];
  const void* W1   = d_in[4];
  const void* b1   = d_in[5];
  const void* Wc0  = d_in[6];
  const void* bc0  = d_in[7];
  const void* Wc1  = d_in[8];
  const void* bc1  = d_in[9];
  const void* Wout = d_in[10];
  const void* bout = d_in[11];
  const void *bn1g = d_in[12], *bn1b = d_in[13], *bn1rm = d_in[14], *bn1rv = d_in[15];
  const void *bc0g = d_in[16], *bc0b = d_in[17], *bc0rm = d_in[18], *bc0rv = d_in[19];
  const void *bc1g = d_in[20], *bc1b = d_in[21], *bc1rm = d_in[22], *bc1rv = d_in[23];
  const void *bn2g = d_in[24], *bn2b = d_in[25], *bn2rm = d_in[26], *bn2rv = d_in[27];
  (void)in_sizes; (void)n_in; (void)out_size; (void)ws_size;

  // workspace carve (~139 MB total)
  char* w = (char*)d_ws;
  auto carve = [&](size_t bytes) {
    char* p = w;
    w += (bytes + 255) & ~(size_t)255;
    return p;
  };
  int*   flags  = (int*)  carve(256);
  float* dinv   = (float*)carve(sizeof(float) * NN);
  int*   cnt    = (int*)  carve(sizeof(int) * NN);
  int*   fill   = (int*)  carve(sizeof(int) * NN);
  int*   indptr = (int*)  carve(sizeof(int) * (NN + 1));
  int*   bsum   = (int*)  carve(sizeof(int) * 256);
  int*   erow   = (int*)  carve(sizeof(int) * NE);
  int*   ecol   = (int*)  carve(sizeof(int) * NE);
  int*   srcs   = (int*)  carve(sizeof(int) * NE);
  float* Wp     = (float*)carve(sizeof(float) * 384 * 128);
  float* cvec   = (float*)carve(sizeof(float) * 128);
  float* xf     = (float*)carve(sizeof(float) * (size_t)NN * 128);
  float* hws    = (float*)carve(sizeof(float) * (size_t)NN * 128);
  float* r0f    = (float*)carve(sizeof(float) * (size_t)NN * 128);
  float* r1f    = (float*)carve(sizeof(float) * (size_t)NN * 128);
  float* r2f    = (float*)carve(sizeof(float) * (size_t)NN * 128);

  const int gN  = (NN + 255) / 256;
  const int gE  = (NE + 255) / 256;
  const int nb  = (NN + 255) / 256;      // 196 scan blocks
  const int gG  = (NN + 63) / 64;        // gemm row tiles
  const int gA  = (NN + 3) / 4;          // 4 waves/block, 1 node/wave

  k_sniff<<<1, 256, 0, stream>>>(x, ei, flags);
  k_cvt_edges<<<gE, 256, 0, stream>>>(ei, erow, ecol, flags);
  k_cvt_x<<<(NN * 128 + 255) / 256, 256, 0, stream>>>(x, xf, flags);
  k_zero_int<<<gN, 256, 0, stream>>>(cnt, NN);
  k_zero_int<<<gN, 256, 0, stream>>>(fill, NN);
  k_count<<<gE, 256, 0, stream>>>(ecol, cnt);
  k_dinv<<<gN, 256, 0, stream>>>(cnt, dinv);
  k_scan1<<<nb, 256, 0, stream>>>(cnt, indptr, bsum, NN);
  k_scan2<<<1, 256, 0, stream>>>(bsum, nb);
  k_scan3<<<(NN + 1 + 255) / 256, 256, 0, stream>>>(indptr, bsum, NN, nb);
  k_fill<<<gE, 256, 0, stream>>>(erow, ecol, indptr, fill, srcs);

  const size_t offO  = 0;
  const size_t offR0 = (size_t)NN * 64;
  const size_t offR1 = offR0 + (size_t)NN * 128;
  const size_t offR2 = offR1 + (size_t)NN * 128;

  // L1: bn1 + W1 (128->128), relu -> r0
  k_prep_w<<<(128 * 128 + 255) / 256, 256, 0, stream>>>(W1, bn1g, bn1rv, Wp, 128, 128, flags);
  k_prep_c<<<1, 128, 0, stream>>>(W1, bn1g, bn1b, bn1rm, bn1rv, cvec, 128, 128, flags);
  k_gemm<128><<<gG, 256, 0, stream>>>(xf, nullptr, nullptr, Wp, cvec, dinv, hws, 128);
  k_agg<2, true><<<gA, 256, 0, stream>>>(hws, indptr, srcs, dinv, b1, d_out, offR0, r0f, flags);

  // L2: bnc0 + Wc0 (128->128), relu -> r1
  k_prep_w<<<(128 * 128 + 255) / 256, 256, 0, stream>>>(Wc0, bc0g, bc0rv, Wp, 128, 128, flags);
  k_prep_c<<<1, 128, 0, stream>>>(Wc0, bc0g, bc0b, bc0rm, bc0rv, cvec, 128, 128, flags);
  k_gemm<128><<<gG, 256, 0, stream>>>(r0f, nullptr, nullptr, Wp, cvec, dinv, hws, 128);
  k_agg<2, true><<<gA, 256, 0, stream>>>(hws, indptr, srcs, dinv, bc0, d_out, offR1, r1f, flags);

  // L3: bnc1 + Wc1 (256->128) on concat(r0,r1), relu -> r2
  k_prep_w<<<(256 * 128 + 255) / 256, 256, 0, stream>>>(Wc1, bc1g, bc1rv, Wp, 256, 128, flags);
  k_prep_c<<<1, 128, 0, stream>>>(Wc1, bc1g, bc1b, bc1rm, bc1rv, cvec, 256, 128, flags);
  k_gemm<128><<<gG, 256, 0, stream>>>(r0f, r1f, nullptr, Wp, cvec, dinv, hws, 256);
  k_agg<2, true><<<gA, 256, 0, stream>>>(hws, indptr, srcs, dinv, bc1, d_out, offR2, r2f, flags);

  // L4: bn2 + Wout (384->64) on concat(r0,r1,r2), no relu -> out
  k_prep_w<<<(384 * 64 + 255) / 256, 256, 0, stream>>>(Wout, bn2g, bn2rv, Wp, 384, 64, flags);
  k_prep_c<<<1, 128, 0, stream>>>(Wout, bn2g, bn2b, bn2rm, bn2rv, cvec, 384, 64, flags);
  k_gemm<64><<<gG, 256, 0, stream>>>(r0f, r1f, r2f, Wp, cvec, dinv, hws, 384);
  k_agg<1, false><<<gA, 256, 0, stream>>>(hws, indptr, srcs, dinv, bout, d_out, offO, nullptr, flags);
}

// Round 2
// 619.338 us; speedup vs baseline: 1.6311x; 1.6311x over previous
//
#include <hip/hip_runtime.h>
#include <hip/hip_bf16.h>
#include <stdint.h>

#define NN 50000
#define NE 800000

using bf16 = __hip_bfloat16;

// ---------- dtype helpers ----------
__device__ __forceinline__ float bf2f_bits(unsigned short u) {
  unsigned int x = ((unsigned int)u) << 16;
  float f;
  __builtin_memcpy(&f, &x, 4);
  return f;
}
__device__ __forceinline__ unsigned short f2bf_bits(float f) {
  unsigned int x;
  __builtin_memcpy(&x, &f, 4);
  unsigned int lsb = (x >> 16) & 1u;
  x += 0x7fffu + lsb;                       // round to nearest even
  return (unsigned short)(x >> 16);
}
__device__ __forceinline__ float loadf(const void* base, size_t idx, int isbf) {
  if (isbf) return bf2f_bits(((const unsigned short*)base)[idx]);
  return ((const float*)base)[idx];
}

// ---------- dtype sniffing (deterministic, graph-safe) ----------
// flags[0]=1 -> float tensors are bf16 on device, else fp32
// flags[1]=1 -> edge_index is int64 on device, else int32
__global__ void k_sniff(const void* x, const void* ei, int* flags) {
  __shared__ int badbf;
  __shared__ int zodd;
  int tid = threadIdx.x;
  if (tid == 0) { badbf = 0; zodd = 0; }
  __syncthreads();
  unsigned short u = ((const unsigned short*)x)[tid];
  float v = bf2f_bits(u);
  float av = fabsf(v);
  int ok = (av == 0.0f) || (av > 1e-8f && av < 1e8f);
  if (!ok) atomicAdd(&badbf, 1);
  int e32 = ((const int*)ei)[tid];
  if ((tid & 1) && e32 == 0) atomicAdd(&zodd, 1);
  __syncthreads();
  if (tid == 0) {
    flags[0] = (badbf <= 12) ? 1 : 0;   // genuine bf16 data: ~0 bad; fp32 read as bf16: ~100 bad
    flags[1] = (zodd >= 100) ? 1 : 0;   // int64 (<2^31 values): all 128 odd words zero
  }
}

__global__ void k_cvt_edges(const void* ei, int* erow, int* ecol, const int* flags) {
  int e = blockIdx.x * 256 + threadIdx.x;
  if (e >= NE) return;
  if (flags[1]) {
    const long long* p = (const long long*)ei;
    erow[e] = (int)p[e];
    ecol[e] = (int)p[NE + e];
  } else {
    const int* p = (const int*)ei;
    erow[e] = p[e];
    ecol[e] = p[NE + e];
  }
}

__global__ void k_cvt_x(const void* x, float* xf, const int* flags) {
  int i = blockIdx.x * 256 + threadIdx.x;
  if (i < NN * 128) xf[i] = loadf(x, (size_t)i, flags[0]);
}

// ---------- degree / CSR ----------
__global__ void k_zero_int(int* p, int n) {
  int i = blockIdx.x * 256 + threadIdx.x;
  if (i < n) p[i] = 0;
}
__global__ void k_count(const int* ecol, int* cnt) {
  int e = blockIdx.x * 256 + threadIdx.x;
  if (e < NE) atomicAdd(&cnt[ecol[e]], 1);
}
__global__ void k_dinv(const int* cnt, float* dinv) {
  int i = blockIdx.x * 256 + threadIdx.x;
  if (i < NN) dinv[i] = rsqrtf((float)(cnt[i] + 1));   // +1 self loop
}
__global__ void k_scan1(const int* cnt, int* indptr, int* bsum, int n) {
  __shared__ int sm[256];
  int tid = threadIdx.x;
  int i = blockIdx.x * 256 + tid;
  int v = (i < n) ? cnt[i] : 0;
  sm[tid] = v;
  __syncthreads();
  for (int off = 1; off < 256; off <<= 1) {
    int t = (tid >= off) ? sm[tid - off] : 0;
    __syncthreads();
    sm[tid] += t;
    __syncthreads();
  }
  if (i < n) indptr[i] = sm[tid] - v;          // local exclusive
  if (tid == 255) bsum[blockIdx.x] = sm[255];  // block total
}
__global__ void k_scan2(int* bsum, int nb) {
  __shared__ int sm[256];
  int tid = threadIdx.x;
  int v = (tid < nb) ? bsum[tid] : 0;
  sm[tid] = v;
  __syncthreads();
  for (int off = 1; off < 256; off <<= 1) {
    int t = (tid >= off) ? sm[tid - off] : 0;
    __syncthreads();
    sm[tid] += t;
    __syncthreads();
  }
  if (tid < nb) bsum[tid] = sm[tid] - v;       // exclusive block offsets
  if (tid == 0) bsum[nb] = sm[255];            // grand total
}
__global__ void k_scan3(int* indptr, const int* bsum, int n, int nb) {
  int i = blockIdx.x * 256 + threadIdx.x;
  if (i < n) indptr[i] += bsum[i >> 8];
  else if (i == n) indptr[n] = bsum[nb];
}
__global__ void k_fill(const int* erow, const int* ecol, const int* indptr,
                       int* fill, int* srcs) {
  int e = blockIdx.x * 256 + threadIdx.x;
  if (e >= NE) return;
  int c = ecol[e];
  int p = indptr[c] + atomicAdd(&fill[c], 1);
  srcs[p] = erow[e];
}

// ---------- BN folding:  bn(h)@W = h@W' + c ----------
// s[k] = g[k]*rsqrt(rv[k]+eps); t[k] = b[k] - rm[k]*s[k]
__global__ void k_prep_st(const void* g, const void* b, const void* rm, const void* rv,
                          float* s, float* t, int K, const int* flags) {
  int k = blockIdx.x * 256 + threadIdx.x;
  if (k >= K) return;
  int isbf = flags[0];
  float sv = loadf(g, k, isbf) * rsqrtf(loadf(rv, k, isbf) + 1e-5f);
  s[k] = sv;
  t[k] = loadf(b, k, isbf) - loadf(rm, k, isbf) * sv;
}
__global__ void k_prep_w2(const void* W, const float* __restrict__ s,
                          float* Wp, int K, int NOUT, const int* flags) {
  int idx = blockIdx.x * 256 + threadIdx.x;
  if (idx >= K * NOUT) return;
  Wp[idx] = s[idx / NOUT] * loadf(W, (size_t)idx, flags[0]);
}
// one block (64 lanes) per output column j; strided K reduce + wave reduce
__global__ void k_prep_c2(const void* W, const float* __restrict__ t,
                          float* cvec, int K, int NOUT, const int* flags) {
  int j = blockIdx.x;
  int lane = threadIdx.x;
  int isbf = flags[0];
  float acc = 0.f;
  for (int k = lane; k < K; k += 64)
    acc += t[k] * loadf(W, (size_t)k * NOUT + j, isbf);
#pragma unroll
  for (int off = 32; off; off >>= 1) acc += __shfl_down(acc, off);
  if (lane == 0) cvec[j] = acc;
}

// ---------- GEMM: hws[i][j] = dinv[i] * ( h[i,:] @ Wp[:,j] + c[j] ) ----------
// h regions are fp32 [NN][128] each (K/128 regions). 64-row tiles, Kc=64 chunks.
template <int NOUT>
__global__ __launch_bounds__(256) void k_gemm(
    const float* __restrict__ h0, const float* __restrict__ h1,
    const float* __restrict__ h2, const float* __restrict__ Wp,
    const float* __restrict__ cvec, const float* __restrict__ dinv,
    float* __restrict__ hws, int K) {
  constexpr int NCQ = NOUT / 8;   // col groups of 8
  constexpr int NRQ = 256 / NCQ;  // row groups
  constexpr int RPT = 64 / NRQ;   // rows per thread
  __shared__ float h_lds[64][65];       // +1 pad: rq reads conflict-free
  __shared__ float w_lds[64][NOUT];
  int tid = threadIdx.x;
  int row0 = blockIdx.x * 64;
  int rq = tid % NRQ;             // lanes 0..NRQ-1 share cq -> w broadcast
  int cq = tid / NRQ;
  float acc[RPT][8];
#pragma unroll
  for (int r = 0; r < RPT; ++r)
#pragma unroll
    for (int c = 0; c < 8; ++c) acc[r][c] = 0.f;

  for (int k0 = 0; k0 < K; k0 += 64) {
    // stage W chunk (64 x NOUT fp32), coalesced float4
    {
      const float* wsrc = Wp + (size_t)k0 * NOUT;
      constexpr int TOT4 = 64 * NOUT / 4;
      for (int u = tid; u < TOT4; u += 256) {
        float4 v = *reinterpret_cast<const float4*>(wsrc + (size_t)u * 4);
        int kk = (u * 4) / NOUT, cc = (u * 4) % NOUT;
        *reinterpret_cast<float4*>(&w_lds[kk][cc]) = v;
      }
    }
    // stage h chunk (64 rows x 64 k-cols); chunk never straddles a 128-region
    {
      int rg = k0 >> 7;
      int ko = k0 & 127;
      const float* fsrc = (rg == 0) ? h0 : ((rg == 1) ? h1 : h2);
      for (int u = tid; u < 64 * 16; u += 256) {
        int r = u >> 4, c4 = (u & 15) * 4;
        int grow = row0 + r;
        float v0 = 0.f, v1 = 0.f, v2 = 0.f, v3 = 0.f;
        if (grow < NN) {
          float4 v = *reinterpret_cast<const float4*>(fsrc + (size_t)grow * 128 + ko + c4);
          v0 = v.x; v1 = v.y; v2 = v.z; v3 = v.w;
        }
        h_lds[r][c4 + 0] = v0; h_lds[r][c4 + 1] = v1;
        h_lds[r][c4 + 2] = v2; h_lds[r][c4 + 3] = v3;
      }
    }
    __syncthreads();
#pragma unroll 4
    for (int kk = 0; kk < 64; ++kk) {
      float a[RPT];
#pragma unroll
      for (int r = 0; r < RPT; ++r) a[r] = h_lds[rq * RPT + r][kk];
      float4 w0 = *reinterpret_cast<const float4*>(&w_lds[kk][cq * 8]);
      float4 w1 = *reinterpret_cast<const float4*>(&w_lds[kk][cq * 8 + 4]);
#pragma unroll
      for (int r = 0; r < RPT; ++r) {
        acc[r][0] += a[r] * w0.x; acc[r][1] += a[r] * w0.y;
        acc[r][2] += a[r] * w0.z; acc[r][3] += a[r] * w0.w;
        acc[r][4] += a[r] * w1.x; acc[r][5] += a[r] * w1.y;
        acc[r][6] += a[r] * w1.z; acc[r][7] += a[r] * w1.w;
      }
    }
    __syncthreads();
  }
  float4 cv0 = *reinterpret_cast<const float4*>(cvec + cq * 8);
  float4 cv1 = *reinterpret_cast<const float4*>(cvec + cq * 8 + 4);
#pragma unroll
  for (int r = 0; r < RPT; ++r) {
    int grow = row0 + rq * RPT + r;
    if (grow >= NN) continue;
    float dv = dinv[grow];
    float4 o0, o1;
    o0.x = dv * (acc[r][0] + cv0.x); o0.y = dv * (acc[r][1] + cv0.y);
    o0.z = dv * (acc[r][2] + cv0.z); o0.w = dv * (acc[r][3] + cv0.w);
    o1.x = dv * (acc[r][4] + cv1.x); o1.y = dv * (acc[r][5] + cv1.y);
    o1.z = dv * (acc[r][6] + cv1.z); o1.w = dv * (acc[r][7] + cv1.w);
    float* dst = hws + (size_t)grow * NOUT + cq * 8;
    *reinterpret_cast<float4*>(dst) = o0;
    *reinterpret_cast<float4*>(dst + 4) = o1;
  }
}

// ---------- aggregation: one wave per node, gather from CSR ----------
template <int DPL, bool RELU>
__global__ __launch_bounds__(256) void k_agg(
    const float* __restrict__ hws, const int* __restrict__ indptr,
    const int* __restrict__ srcs, const float* __restrict__ dinv,
    const void* __restrict__ bias, void* __restrict__ dout, size_t region_off,
    float* __restrict__ outf, const int* __restrict__ flags) {
  constexpr int NOUT = DPL * 64;
  int gw = (blockIdx.x * 256 + threadIdx.x) >> 6;
  int lane = threadIdx.x & 63;
  if (gw >= NN) return;
  int isbf = flags[0];
  float acc0[DPL], acc1[DPL];
  const float* self = hws + (size_t)gw * NOUT + lane * DPL;
#pragma unroll
  for (int d = 0; d < DPL; ++d) { acc0[d] = self[d]; acc1[d] = 0.f; }
  int e0 = indptr[gw], e1 = indptr[gw + 1];
  int e = e0;
  for (; e + 1 < e1; e += 2) {   // 2-edge unroll for memory-level parallelism
    int s0 = srcs[e], s1 = srcs[e + 1];
    const float* p0 = hws + (size_t)s0 * NOUT + lane * DPL;
    const float* p1 = hws + (size_t)s1 * NOUT + lane * DPL;
    if constexpr (DPL == 2) {
      float2 v0 = *reinterpret_cast<const float2*>(p0);
      float2 v1 = *reinterpret_cast<const float2*>(p1);
      acc0[0] += v0.x; acc0[1] += v0.y;
      acc1[0] += v1.x; acc1[1] += v1.y;
    } else {
      acc0[0] += p0[0];
      acc1[0] += p1[0];
    }
  }
  if (e < e1) {
    int s0 = srcs[e];
    const float* p0 = hws + (size_t)s0 * NOUT + lane * DPL;
    if constexpr (DPL == 2) {
      float2 v0 = *reinterpret_cast<const float2*>(p0);
      acc0[0] += v0.x; acc0[1] += v0.y;
    } else {
      acc0[0] += p0[0];
    }
  }
  float dv = dinv[gw];
#pragma unroll
  for (int d = 0; d < DPL; ++d) {
    float o = dv * (acc0[d] + acc1[d]) + loadf(bias, (size_t)(lane * DPL + d), isbf);
    if (RELU) o = fmaxf(o, 0.f);
    size_t eo = region_off + (size_t)gw * NOUT + lane * DPL + d;
    if (isbf) ((unsigned short*)dout)[eo] = f2bf_bits(o);
    else      ((float*)dout)[eo] = o;
    if (outf) outf[(size_t)gw * NOUT + lane * DPL + d] = o;
  }
}

extern "C" void kernel_launch(void* const* d_in, const int* in_sizes, int n_in,
                              void* d_out, int out_size, void* d_ws, size_t ws_size,
                              hipStream_t stream) {
  const void* x    = d_in[0];
  const void* ei   = d_in[1];
  const void* W1   = d_in[4];
  const void* b1   = d_in[5];
  const void* Wc0  = d_in[6];
  const void* bc0  = d_in[7];
  const void* Wc1  = d_in[8];
  const void* bc1  = d_in[9];
  const void* Wout = d_in[10];
  const void* bout = d_in[11];
  const void *bn1g = d_in[12], *bn1b = d_in[13], *bn1rm = d_in[14], *bn1rv = d_in[15];
  const void *bc0g = d_in[16], *bc0b = d_in[17], *bc0rm = d_in[18], *bc0rv = d_in[19];
  const void *bc1g = d_in[20], *bc1b = d_in[21], *bc1rm = d_in[22], *bc1rv = d_in[23];
  const void *bn2g = d_in[24], *bn2b = d_in[25], *bn2rm = d_in[26], *bn2rv = d_in[27];
  (void)in_sizes; (void)n_in; (void)out_size; (void)ws_size;

  // workspace carve (~139 MB total)
  char* w = (char*)d_ws;
  auto carve = [&](size_t bytes) {
    char* p = w;
    w += (bytes + 255) & ~(size_t)255;
    return p;
  };
  int*   flags  = (int*)  carve(256);
  float* dinv   = (float*)carve(sizeof(float) * NN);
  int*   cnt    = (int*)  carve(sizeof(int) * NN);
  int*   fill   = (int*)  carve(sizeof(int) * NN);
  int*   indptr = (int*)  carve(sizeof(int) * (NN + 1));
  int*   bsum   = (int*)  carve(sizeof(int) * 256);
  int*   erow   = (int*)  carve(sizeof(int) * NE);
  int*   ecol   = (int*)  carve(sizeof(int) * NE);
  int*   srcs   = (int*)  carve(sizeof(int) * NE);
  float* Wp     = (float*)carve(sizeof(float) * 384 * 128);
  float* cvec   = (float*)carve(sizeof(float) * 128);
  float* svec   = (float*)carve(sizeof(float) * 384);
  float* tvec   = (float*)carve(sizeof(float) * 384);
  float* xf     = (float*)carve(sizeof(float) * (size_t)NN * 128);
  float* hws    = (float*)carve(sizeof(float) * (size_t)NN * 128);
  float* r0f    = (float*)carve(sizeof(float) * (size_t)NN * 128);
  float* r1f    = (float*)carve(sizeof(float) * (size_t)NN * 128);
  float* r2f    = (float*)carve(sizeof(float) * (size_t)NN * 128);

  const int gN  = (NN + 255) / 256;
  const int gE  = (NE + 255) / 256;
  const int nb  = (NN + 255) / 256;      // 196 scan blocks
  const int gG  = (NN + 63) / 64;        // gemm row tiles
  const int gA  = (NN + 3) / 4;          // 4 waves/block, 1 node/wave

  k_sniff<<<1, 256, 0, stream>>>(x, ei, flags);
  k_cvt_edges<<<gE, 256, 0, stream>>>(ei, erow, ecol, flags);
  k_cvt_x<<<(NN * 128 + 255) / 256, 256, 0, stream>>>(x, xf, flags);
  k_zero_int<<<gN, 256, 0, stream>>>(cnt, NN);
  k_zero_int<<<gN, 256, 0, stream>>>(fill, NN);
  k_count<<<gE, 256, 0, stream>>>(ecol, cnt);
  k_dinv<<<gN, 256, 0, stream>>>(cnt, dinv);
  k_scan1<<<nb, 256, 0, stream>>>(cnt, indptr, bsum, NN);
  k_scan2<<<1, 256, 0, stream>>>(bsum, nb);
  k_scan3<<<(NN + 1 + 255) / 256, 256, 0, stream>>>(indptr, bsum, NN, nb);
  k_fill<<<gE, 256, 0, stream>>>(erow, ecol, indptr, fill, srcs);

  const size_t offO  = 0;
  const size_t offR0 = (size_t)NN * 64;
  const size_t offR1 = offR0 + (size_t)NN * 128;
  const size_t offR2 = offR1 + (size_t)NN * 128;

  // L1: bn1 + W1 (128->128), relu -> r0
  k_prep_st<<<1, 256, 0, stream>>>(bn1g, bn1b, bn1rm, bn1rv, svec, tvec, 128, flags);
  k_prep_w2<<<(128 * 128 + 255) / 256, 256, 0, stream>>>(W1, svec, Wp, 128, 128, flags);
  k_prep_c2<<<128, 64, 0, stream>>>(W1, tvec, cvec, 128, 128, flags);
  k_gemm<128><<<gG, 256, 0, stream>>>(xf, nullptr, nullptr, Wp, cvec, dinv, hws, 128);
  k_agg<2, true><<<gA, 256, 0, stream>>>(hws, indptr, srcs, dinv, b1, d_out, offR0, r0f, flags);

  // L2: bnc0 + Wc0 (128->128), relu -> r1
  k_prep_st<<<1, 256, 0, stream>>>(bc0g, bc0b, bc0rm, bc0rv, svec, tvec, 128, flags);
  k_prep_w2<<<(128 * 128 + 255) / 256, 256, 0, stream>>>(Wc0, svec, Wp, 128, 128, flags);
  k_prep_c2<<<128, 64, 0, stream>>>(Wc0, tvec, cvec, 128, 128, flags);
  k_gemm<128><<<gG, 256, 0, stream>>>(r0f, nullptr, nullptr, Wp, cvec, dinv, hws, 128);
  k_agg<2, true><<<gA, 256, 0, stream>>>(hws, indptr, srcs, dinv, bc0, d_out, offR1, r1f, flags);

  // L3: bnc1 + Wc1 (256->128) on concat(r0,r1), relu -> r2
  k_prep_st<<<1, 256, 0, stream>>>(bc1g, bc1b, bc1rm, bc1rv, svec, tvec, 256, flags);
  k_prep_w2<<<(256 * 128 + 255) / 256, 256, 0, stream>>>(Wc1, svec, Wp, 256, 128, flags);
  k_prep_c2<<<128, 64, 0, stream>>>(Wc1, tvec, cvec, 256, 128, flags);
  k_gemm<128><<<gG, 256, 0, stream>>>(r0f, r1f, nullptr, Wp, cvec, dinv, hws, 256);
  k_agg<2, true><<<gA, 256, 0, stream>>>(hws, indptr, srcs, dinv, bc1, d_out, offR2, r2f, flags);

  // L4: bn2 + Wout (384->64) on concat(r0,r1,r2), no relu -> out
  k_prep_st<<<2, 256, 0, stream>>>(bn2g, bn2b, bn2rm, bn2rv, svec, tvec, 384, flags);
  k_prep_w2<<<(384 * 64 + 255) / 256, 256, 0, stream>>>(Wout, svec, Wp, 384, 64, flags);
  k_prep_c2<<<64, 64, 0, stream>>>(Wout, tvec, cvec, 384, 64, flags);
  k_gemm<64><<<gG, 256, 0, stream>>>(r0f, r1f, r2f, Wp, cvec, dinv, hws, 384);
  k_agg<1, false><<<gA, 256, 0, stream>>>(hws, indptr, srcs, dinv, bout, d_out, offO, nullptr, flags);
}

// Round 3
// 485.711 us; speedup vs baseline: 2.0798x; 1.2751x over previous
//
#include <hip/hip_runtime.h>
#include <hip/hip_bf16.h>
#include <stdint.h>

#define NN 50000
#define NE 800000

typedef unsigned short ushort8 __attribute__((ext_vector_type(8)));

// ---------- dtype helpers ----------
__device__ __forceinline__ float bf2f_bits(unsigned short u) {
  unsigned int x = ((unsigned int)u) << 16;
  float f;
  __builtin_memcpy(&f, &x, 4);
  return f;
}
__device__ __forceinline__ unsigned short f2bf_bits(float f) {
  unsigned int x;
  __builtin_memcpy(&x, &f, 4);
  unsigned int lsb = (x >> 16) & 1u;
  x += 0x7fffu + lsb;                       // round to nearest even
  return (unsigned short)(x >> 16);
}
__device__ __forceinline__ float loadf(const void* base, size_t idx, int isbf) {
  if (isbf) return bf2f_bits(((const unsigned short*)base)[idx]);
  return ((const float*)base)[idx];
}

// ---------- dtype sniffing (deterministic, graph-safe) ----------
// flags[0]=1 -> float tensors are bf16 on device, else fp32
// flags[1]=1 -> edge_index is int64 on device, else int32
__global__ void k_sniff(const void* x, const void* ei, int* flags) {
  __shared__ int badbf;
  __shared__ int zodd;
  int tid = threadIdx.x;
  if (tid == 0) { badbf = 0; zodd = 0; }
  __syncthreads();
  unsigned short u = ((const unsigned short*)x)[tid];
  float v = bf2f_bits(u);
  float av = fabsf(v);
  int ok = (av == 0.0f) || (av > 1e-8f && av < 1e8f);
  if (!ok) atomicAdd(&badbf, 1);
  int e32 = ((const int*)ei)[tid];
  if ((tid & 1) && e32 == 0) atomicAdd(&zodd, 1);
  __syncthreads();
  if (tid == 0) {
    flags[0] = (badbf <= 12) ? 1 : 0;
    flags[1] = (zodd >= 100) ? 1 : 0;
  }
}

__global__ void k_cvt_edges(const void* ei, int* erow, int* ecol, const int* flags) {
  int e = blockIdx.x * 256 + threadIdx.x;
  if (e >= NE) return;
  if (flags[1]) {
    const long long* p = (const long long*)ei;
    erow[e] = (int)p[e];
    ecol[e] = (int)p[NE + e];
  } else {
    const int* p = (const int*)ei;
    erow[e] = p[e];
    ecol[e] = p[NE + e];
  }
}

// x (fp32 or bf16) -> bf16 internal, 4 elems/thread
__global__ void k_cvt_xb(const void* x, unsigned short* xb, const int* flags) {
  int i4 = (blockIdx.x * 256 + threadIdx.x) * 4;
  if (i4 >= NN * 128) return;
  int isbf = flags[0];
  if (isbf) {
    *reinterpret_cast<uint2*>(xb + i4) =
        *reinterpret_cast<const uint2*>((const unsigned short*)x + i4);
  } else {
    float4 v = *reinterpret_cast<const float4*>((const float*)x + i4);
    xb[i4 + 0] = f2bf_bits(v.x); xb[i4 + 1] = f2bf_bits(v.y);
    xb[i4 + 2] = f2bf_bits(v.z); xb[i4 + 3] = f2bf_bits(v.w);
  }
}

// ---------- degree / CSR ----------
__global__ void k_zero_int(int* p, int n) {
  int i = blockIdx.x * 256 + threadIdx.x;
  if (i < n) p[i] = 0;
}
__global__ void k_count(const int* ecol, int* cnt) {
  int e = blockIdx.x * 256 + threadIdx.x;
  if (e < NE) atomicAdd(&cnt[ecol[e]], 1);
}
__global__ void k_dinv(const int* cnt, float* dinv) {
  int i = blockIdx.x * 256 + threadIdx.x;
  if (i < NN) dinv[i] = rsqrtf((float)(cnt[i] + 1));   // +1 self loop
}
__global__ void k_scan1(const int* cnt, int* indptr, int* bsum, int n) {
  __shared__ int sm[256];
  int tid = threadIdx.x;
  int i = blockIdx.x * 256 + tid;
  int v = (i < n) ? cnt[i] : 0;
  sm[tid] = v;
  __syncthreads();
  for (int off = 1; off < 256; off <<= 1) {
    int t = (tid >= off) ? sm[tid - off] : 0;
    __syncthreads();
    sm[tid] += t;
    __syncthreads();
  }
  if (i < n) indptr[i] = sm[tid] - v;
  if (tid == 255) bsum[blockIdx.x] = sm[255];
}
__global__ void k_scan2(int* bsum, int nb) {
  __shared__ int sm[256];
  int tid = threadIdx.x;
  int v = (tid < nb) ? bsum[tid] : 0;
  sm[tid] = v;
  __syncthreads();
  for (int off = 1; off < 256; off <<= 1) {
    int t = (tid >= off) ? sm[tid - off] : 0;
    __syncthreads();
    sm[tid] += t;
    __syncthreads();
  }
  if (tid < nb) bsum[tid] = sm[tid] - v;
  if (tid == 0) bsum[nb] = sm[255];
}
__global__ void k_scan3(int* indptr, const int* bsum, int n, int nb) {
  int i = blockIdx.x * 256 + threadIdx.x;
  if (i < n) indptr[i] += bsum[i >> 8];
  else if (i == n) indptr[n] = bsum[nb];
}
__global__ void k_fill(const int* erow, const int* ecol, const int* indptr,
                       int* fill, int* srcs) {
  int e = blockIdx.x * 256 + threadIdx.x;
  if (e >= NE) return;
  int c = ecol[e];
  int p = indptr[c] + atomicAdd(&fill[c], 1);
  srcs[p] = erow[e];
}

// ---------- BN folding:  bn(h)@W = h@W' + c ----------
__global__ void k_prep_w(const void* W, const void* g, const void* rv,
                         float* Wp, int K, int NOUT, const int* flags) {
  int idx = blockIdx.x * 256 + threadIdx.x;
  if (idx >= K * NOUT) return;
  int isbf = flags[0];
  int k = idx / NOUT;
  float s = loadf(g, k, isbf) * rsqrtf(loadf(rv, k, isbf) + 1e-5f);
  Wp[idx] = s * loadf(W, (size_t)idx, isbf);
}
// one block (64 lanes) per output column j
__global__ void k_prep_c(const void* W, const void* g, const void* b,
                         const void* rm, const void* rv, float* cvec,
                         int K, int NOUT, const int* flags) {
  int j = blockIdx.x;
  int lane = threadIdx.x;
  int isbf = flags[0];
  float acc = 0.f;
  for (int k = lane; k < K; k += 64) {
    float s = loadf(g, k, isbf) * rsqrtf(loadf(rv, k, isbf) + 1e-5f);
    float t = loadf(b, k, isbf) - loadf(rm, k, isbf) * s;
    acc += t * loadf(W, (size_t)k * NOUT + j, isbf);
  }
#pragma unroll
  for (int off = 32; off; off >>= 1) acc += __shfl_down(acc, off);
  if (lane == 0) cvec[j] = acc;
}

// ---------- GEMM: hb[i][j] = bf16( dinv[i] * ( h[i,:] @ Wp[:,j] + c[j] ) ) ----------
// h regions are bf16 [NN][128] each. 64-row tiles, Kc=64 chunks, fp32 FMA compute.
template <int NOUT>
__global__ __launch_bounds__(256) void k_gemm(
    const unsigned short* __restrict__ h0, const unsigned short* __restrict__ h1,
    const unsigned short* __restrict__ h2, const float* __restrict__ Wp,
    const float* __restrict__ cvec, const float* __restrict__ dinv,
    unsigned short* __restrict__ hb, int K) {
  constexpr int NCQ = NOUT / 8;   // col groups of 8
  constexpr int NRQ = 256 / NCQ;  // row groups
  constexpr int RPT = 64 / NRQ;   // rows per thread
  __shared__ float h_lds[64][65];       // +1 pad
  __shared__ float w_lds[64][NOUT];
  int tid = threadIdx.x;
  int row0 = blockIdx.x * 64;
  int rq = tid % NRQ;
  int cq = tid / NRQ;
  float acc[RPT][8];
#pragma unroll
  for (int r = 0; r < RPT; ++r)
#pragma unroll
    for (int c = 0; c < 8; ++c) acc[r][c] = 0.f;

  for (int k0 = 0; k0 < K; k0 += 64) {
    // stage W chunk (64 x NOUT fp32), coalesced float4
    {
      const float* wsrc = Wp + (size_t)k0 * NOUT;
      constexpr int TOT4 = 64 * NOUT / 4;
      for (int u = tid; u < TOT4; u += 256) {
        float4 v = *reinterpret_cast<const float4*>(wsrc + (size_t)u * 4);
        int kk = (u * 4) / NOUT, cc = (u * 4) % NOUT;
        *reinterpret_cast<float4*>(&w_lds[kk][cc]) = v;
      }
    }
    // stage h chunk: 64 rows x 64 k-cols bf16 -> fp32 LDS
    {
      int rg = k0 >> 7;
      int ko = k0 & 127;
      const unsigned short* fsrc = (rg == 0) ? h0 : ((rg == 1) ? h1 : h2);
      for (int u = tid; u < 64 * 8; u += 256) {   // 8 x ushort8 per row
        int r = u >> 3, c8 = (u & 7) * 8;
        int grow = row0 + r;
        ushort8 v = (ushort8)0;
        if (grow < NN)
          v = *reinterpret_cast<const ushort8*>(fsrc + (size_t)grow * 128 + ko + c8);
#pragma unroll
        for (int j = 0; j < 8; ++j) h_lds[r][c8 + j] = bf2f_bits(v[j]);
      }
    }
    __syncthreads();
#pragma unroll 4
    for (int kk = 0; kk < 64; ++kk) {
      float a[RPT];
#pragma unroll
      for (int r = 0; r < RPT; ++r) a[r] = h_lds[rq * RPT + r][kk];
      float4 w0 = *reinterpret_cast<const float4*>(&w_lds[kk][cq * 8]);
      float4 w1 = *reinterpret_cast<const float4*>(&w_lds[kk][cq * 8 + 4]);
#pragma unroll
      for (int r = 0; r < RPT; ++r) {
        acc[r][0] += a[r] * w0.x; acc[r][1] += a[r] * w0.y;
        acc[r][2] += a[r] * w0.z; acc[r][3] += a[r] * w0.w;
        acc[r][4] += a[r] * w1.x; acc[r][5] += a[r] * w1.y;
        acc[r][6] += a[r] * w1.z; acc[r][7] += a[r] * w1.w;
      }
    }
    __syncthreads();
  }
  float4 cv0 = *reinterpret_cast<const float4*>(cvec + cq * 8);
  float4 cv1 = *reinterpret_cast<const float4*>(cvec + cq * 8 + 4);
#pragma unroll
  for (int r = 0; r < RPT; ++r) {
    int grow = row0 + rq * RPT + r;
    if (grow >= NN) continue;
    float dv = dinv[grow];
    ushort8 o;
    o[0] = f2bf_bits(dv * (acc[r][0] + cv0.x));
    o[1] = f2bf_bits(dv * (acc[r][1] + cv0.y));
    o[2] = f2bf_bits(dv * (acc[r][2] + cv0.z));
    o[3] = f2bf_bits(dv * (acc[r][3] + cv0.w));
    o[4] = f2bf_bits(dv * (acc[r][4] + cv1.x));
    o[5] = f2bf_bits(dv * (acc[r][5] + cv1.y));
    o[6] = f2bf_bits(dv * (acc[r][6] + cv1.z));
    o[7] = f2bf_bits(dv * (acc[r][7] + cv1.w));
    *reinterpret_cast<ushort8*>(hb + (size_t)grow * NOUT + cq * 8) = o;
  }
}

// ---------- aggregation: one wave per node, bf16 gather from CSR ----------
template <int DPL, bool RELU>
__global__ __launch_bounds__(256) void k_agg(
    const unsigned short* __restrict__ hb, const int* __restrict__ indptr,
    const int* __restrict__ srcs, const float* __restrict__ dinv,
    const void* __restrict__ bias, void* __restrict__ dout, size_t region_off,
    unsigned short* __restrict__ rb, const int* __restrict__ flags) {
  constexpr int NOUT = DPL * 64;
  int gw = (blockIdx.x * 256 + threadIdx.x) >> 6;
  int lane = threadIdx.x & 63;
  if (gw >= NN) return;
  int isbf = flags[0];
  int e0 = indptr[gw], e1 = indptr[gw + 1];
  int e = e0;
  float o0, o1;
  if constexpr (DPL == 2) {
    unsigned int v = *reinterpret_cast<const unsigned int*>(
        hb + (size_t)gw * NOUT + lane * 2);
    float s00 = bf2f_bits((unsigned short)v), s01 = bf2f_bits((unsigned short)(v >> 16));
    float s10 = 0.f, s11 = 0.f, s20 = 0.f, s21 = 0.f, s30 = 0.f, s31 = 0.f;
    for (; e + 3 < e1; e += 4) {
      int a = srcs[e], b = srcs[e + 1], c = srcs[e + 2], d = srcs[e + 3];
      unsigned int v0 = *reinterpret_cast<const unsigned int*>(hb + (size_t)a * NOUT + lane * 2);
      unsigned int v1 = *reinterpret_cast<const unsigned int*>(hb + (size_t)b * NOUT + lane * 2);
      unsigned int v2 = *reinterpret_cast<const unsigned int*>(hb + (size_t)c * NOUT + lane * 2);
      unsigned int v3 = *reinterpret_cast<const unsigned int*>(hb + (size_t)d * NOUT + lane * 2);
      s00 += bf2f_bits((unsigned short)v0); s01 += bf2f_bits((unsigned short)(v0 >> 16));
      s10 += bf2f_bits((unsigned short)v1); s11 += bf2f_bits((unsigned short)(v1 >> 16));
      s20 += bf2f_bits((unsigned short)v2); s21 += bf2f_bits((unsigned short)(v2 >> 16));
      s30 += bf2f_bits((unsigned short)v3); s31 += bf2f_bits((unsigned short)(v3 >> 16));
    }
    for (; e < e1; ++e) {
      int a = srcs[e];
      unsigned int v0 = *reinterpret_cast<const unsigned int*>(hb + (size_t)a * NOUT + lane * 2);
      s00 += bf2f_bits((unsigned short)v0); s01 += bf2f_bits((unsigned short)(v0 >> 16));
    }
    float dv = dinv[gw];
    o0 = dv * ((s00 + s10) + (s20 + s30)) + loadf(bias, (size_t)(lane * 2 + 0), isbf);
    o1 = dv * ((s01 + s11) + (s21 + s31)) + loadf(bias, (size_t)(lane * 2 + 1), isbf);
    if (RELU) { o0 = fmaxf(o0, 0.f); o1 = fmaxf(o1, 0.f); }
    size_t eo = region_off + (size_t)gw * NOUT + lane * 2;
    if (isbf) {
      unsigned int pk = (unsigned int)f2bf_bits(o0) | ((unsigned int)f2bf_bits(o1) << 16);
      *reinterpret_cast<unsigned int*>((unsigned short*)dout + eo) = pk;
    } else {
      float2 fo; fo.x = o0; fo.y = o1;
      *reinterpret_cast<float2*>((float*)dout + eo) = fo;
    }
    if (rb) {
      unsigned int pk = (unsigned int)f2bf_bits(o0) | ((unsigned int)f2bf_bits(o1) << 16);
      *reinterpret_cast<unsigned int*>(rb + (size_t)gw * NOUT + lane * 2) = pk;
    }
  } else {
    float s0 = bf2f_bits(hb[(size_t)gw * NOUT + lane]);
    float s1 = 0.f, s2 = 0.f, s3 = 0.f;
    for (; e + 3 < e1; e += 4) {
      int a = srcs[e], b = srcs[e + 1], c = srcs[e + 2], d = srcs[e + 3];
      s0 += bf2f_bits(hb[(size_t)a * NOUT + lane]);
      s1 += bf2f_bits(hb[(size_t)b * NOUT + lane]);
      s2 += bf2f_bits(hb[(size_t)c * NOUT + lane]);
      s3 += bf2f_bits(hb[(size_t)d * NOUT + lane]);
    }
    for (; e < e1; ++e) s0 += bf2f_bits(hb[(size_t)srcs[e] * NOUT + lane]);
    float dv = dinv[gw];
    o0 = dv * ((s0 + s1) + (s2 + s3)) + loadf(bias, (size_t)lane, isbf);
    if (RELU) o0 = fmaxf(o0, 0.f);
    size_t eo = region_off + (size_t)gw * NOUT + lane;
    if (isbf) ((unsigned short*)dout)[eo] = f2bf_bits(o0);
    else      ((float*)dout)[eo] = o0;
    if (rb) rb[(size_t)gw * NOUT + lane] = f2bf_bits(o0);
  }
}

extern "C" void kernel_launch(void* const* d_in, const int* in_sizes, int n_in,
                              void* d_out, int out_size, void* d_ws, size_t ws_size,
                              hipStream_t stream) {
  const void* x    = d_in[0];
  const void* ei   = d_in[1];
  const void* W1   = d_in[4];
  const void* b1   = d_in[5];
  const void* Wc0  = d_in[6];
  const void* bc0  = d_in[7];
  const void* Wc1  = d_in[8];
  const void* bc1  = d_in[9];
  const void* Wout = d_in[10];
  const void* bout = d_in[11];
  const void *bn1g = d_in[12], *bn1b = d_in[13], *bn1rm = d_in[14], *bn1rv = d_in[15];
  const void *bc0g = d_in[16], *bc0b = d_in[17], *bc0rm = d_in[18], *bc0rv = d_in[19];
  const void *bc1g = d_in[20], *bc1b = d_in[21], *bc1rm = d_in[22], *bc1rv = d_in[23];
  const void *bn2g = d_in[24], *bn2b = d_in[25], *bn2rm = d_in[26], *bn2rv = d_in[27];
  (void)in_sizes; (void)n_in; (void)out_size; (void)ws_size;

  char* w = (char*)d_ws;
  auto carve = [&](size_t bytes) {
    char* p = w;
    w += (bytes + 255) & ~(size_t)255;
    return p;
  };
  int*   flags  = (int*)  carve(256);
  float* dinv   = (float*)carve(sizeof(float) * NN);
  int*   cnt    = (int*)  carve(sizeof(int) * NN);
  int*   fill   = (int*)  carve(sizeof(int) * NN);
  int*   indptr = (int*)  carve(sizeof(int) * (NN + 1));
  int*   bsum   = (int*)  carve(sizeof(int) * 256);
  int*   erow   = (int*)  carve(sizeof(int) * NE);
  int*   ecol   = (int*)  carve(sizeof(int) * NE);
  int*   srcs   = (int*)  carve(sizeof(int) * NE);
  float* Wp     = (float*)carve(sizeof(float) * 384 * 128);
  float* cvec   = (float*)carve(sizeof(float) * 128);
  unsigned short* xb  = (unsigned short*)carve(sizeof(short) * (size_t)NN * 128);
  unsigned short* hb  = (unsigned short*)carve(sizeof(short) * (size_t)NN * 128);
  unsigned short* rb0 = (unsigned short*)carve(sizeof(short) * (size_t)NN * 128);
  unsigned short* rb1 = (unsigned short*)carve(sizeof(short) * (size_t)NN * 128);
  unsigned short* rb2 = (unsigned short*)carve(sizeof(short) * (size_t)NN * 128);

  const int gN  = (NN + 255) / 256;
  const int gE  = (NE + 255) / 256;
  const int nb  = (NN + 255) / 256;
  const int gG  = (NN + 63) / 64;
  const int gA  = (NN + 3) / 4;

  k_sniff<<<1, 256, 0, stream>>>(x, ei, flags);
  k_cvt_edges<<<gE, 256, 0, stream>>>(ei, erow, ecol, flags);
  k_cvt_xb<<<(NN * 128 / 4 + 255) / 256, 256, 0, stream>>>(x, xb, flags);
  k_zero_int<<<gN, 256, 0, stream>>>(cnt, NN);
  k_zero_int<<<gN, 256, 0, stream>>>(fill, NN);
  k_count<<<gE, 256, 0, stream>>>(ecol, cnt);
  k_dinv<<<gN, 256, 0, stream>>>(cnt, dinv);
  k_scan1<<<nb, 256, 0, stream>>>(cnt, indptr, bsum, NN);
  k_scan2<<<1, 256, 0, stream>>>(bsum, nb);
  k_scan3<<<(NN + 1 + 255) / 256, 256, 0, stream>>>(indptr, bsum, NN, nb);
  k_fill<<<gE, 256, 0, stream>>>(erow, ecol, indptr, fill, srcs);

  const size_t offO  = 0;
  const size_t offR0 = (size_t)NN * 64;
  const size_t offR1 = offR0 + (size_t)NN * 128;
  const size_t offR2 = offR1 + (size_t)NN * 128;

  // L1: bn1 + W1 (128->128), relu -> r0
  k_prep_w<<<(128 * 128 + 255) / 256, 256, 0, stream>>>(W1, bn1g, bn1rv, Wp, 128, 128, flags);
  k_prep_c<<<128, 64, 0, stream>>>(W1, bn1g, bn1b, bn1rm, bn1rv, cvec, 128, 128, flags);
  k_gemm<128><<<gG, 256, 0, stream>>>(xb, nullptr, nullptr, Wp, cvec, dinv, hb, 128);
  k_agg<2, true><<<gA, 256, 0, stream>>>(hb, indptr, srcs, dinv, b1, d_out, offR0, rb0, flags);

  // L2: bnc0 + Wc0 (128->128), relu -> r1
  k_prep_w<<<(128 * 128 + 255) / 256, 256, 0, stream>>>(Wc0, bc0g, bc0rv, Wp, 128, 128, flags);
  k_prep_c<<<128, 64, 0, stream>>>(Wc0, bc0g, bc0b, bc0rm, bc0rv, cvec, 128, 128, flags);
  k_gemm<128><<<gG, 256, 0, stream>>>(rb0, nullptr, nullptr, Wp, cvec, dinv, hb, 128);
  k_agg<2, true><<<gA, 256, 0, stream>>>(hb, indptr, srcs, dinv, bc0, d_out, offR1, rb1, flags);

  // L3: bnc1 + Wc1 (256->128) on concat(r0,r1), relu -> r2
  k_prep_w<<<(256 * 128 + 255) / 256, 256, 0, stream>>>(Wc1, bc1g, bc1rv, Wp, 256, 128, flags);
  k_prep_c<<<128, 64, 0, stream>>>(Wc1, bc1g, bc1b, bc1rm, bc1rv, cvec, 256, 128, flags);
  k_gemm<128><<<gG, 256, 0, stream>>>(rb0, rb1, nullptr, Wp, cvec, dinv, hb, 256);
  k_agg<2, true><<<gA, 256, 0, stream>>>(hb, indptr, srcs, dinv, bc1, d_out, offR2, rb2, flags);

  // L4: bn2 + Wout (384->64) on concat(r0,r1,r2), no relu -> out
  k_prep_w<<<(384 * 64 + 255) / 256, 256, 0, stream>>>(Wout, bn2g, bn2rv, Wp, 384, 64, flags);
  k_prep_c<<<64, 64, 0, stream>>>(Wout, bn2g, bn2b, bn2rm, bn2rv, cvec, 384, 64, flags);
  k_gemm<64><<<gG, 256, 0, stream>>>(rb0, rb1, rb2, Wp, cvec, dinv, hb, 384);
  k_agg<1, false><<<gA, 256, 0, stream>>>(hb, indptr, srcs, dinv, bout, d_out, offO, nullptr, flags);
}

// Round 4
// 432.073 us; speedup vs baseline: 2.3380x; 1.1241x over previous
//
#include <hip/hip_runtime.h>
#include <hip/hip_bf16.h>
#include <stdint.h>

#define NN 50000
#define NE 800000

typedef unsigned short ushort8 __attribute__((ext_vector_type(8)));
typedef __bf16 bf16x8 __attribute__((ext_vector_type(8)));
typedef float f32x4 __attribute__((ext_vector_type(4)));

// ---------- dtype helpers ----------
__device__ __forceinline__ float bf2f_bits(unsigned short u) {
  unsigned int x = ((unsigned int)u) << 16;
  float f;
  __builtin_memcpy(&f, &x, 4);
  return f;
}
__device__ __forceinline__ unsigned short f2bf_bits(float f) {
  unsigned int x;
  __builtin_memcpy(&x, &f, 4);
  unsigned int lsb = (x >> 16) & 1u;
  x += 0x7fffu + lsb;                       // round to nearest even
  return (unsigned short)(x >> 16);
}
__device__ __forceinline__ float loadf(const void* base, size_t idx, int isbf) {
  if (isbf) return bf2f_bits(((const unsigned short*)base)[idx]);
  return ((const float*)base)[idx];
}

// ---------- dtype sniffing (deterministic, graph-safe) ----------
__global__ void k_sniff(const void* x, const void* ei, int* flags) {
  __shared__ int badbf;
  __shared__ int zodd;
  int tid = threadIdx.x;
  if (tid == 0) { badbf = 0; zodd = 0; }
  __syncthreads();
  unsigned short u = ((const unsigned short*)x)[tid];
  float v = bf2f_bits(u);
  float av = fabsf(v);
  int ok = (av == 0.0f) || (av > 1e-8f && av < 1e8f);
  if (!ok) atomicAdd(&badbf, 1);
  int e32 = ((const int*)ei)[tid];
  if ((tid & 1) && e32 == 0) atomicAdd(&zodd, 1);
  __syncthreads();
  if (tid == 0) {
    flags[0] = (badbf <= 12) ? 1 : 0;
    flags[1] = (zodd >= 100) ? 1 : 0;
  }
}

__global__ void k_cvt_edges(const void* ei, int* erow, int* ecol, const int* flags) {
  int e = blockIdx.x * 256 + threadIdx.x;
  if (e >= NE) return;
  if (flags[1]) {
    const long long* p = (const long long*)ei;
    erow[e] = (int)p[e];
    ecol[e] = (int)p[NE + e];
  } else {
    const int* p = (const int*)ei;
    erow[e] = p[e];
    ecol[e] = p[NE + e];
  }
}

// x (fp32 or bf16) -> bf16 internal, 4 elems/thread
__global__ void k_cvt_xb(const void* x, unsigned short* xb, const int* flags) {
  int i4 = (blockIdx.x * 256 + threadIdx.x) * 4;
  if (i4 >= NN * 128) return;
  int isbf = flags[0];
  if (isbf) {
    *reinterpret_cast<uint2*>(xb + i4) =
        *reinterpret_cast<const uint2*>((const unsigned short*)x + i4);
  } else {
    float4 v = *reinterpret_cast<const float4*>((const float*)x + i4);
    xb[i4 + 0] = f2bf_bits(v.x); xb[i4 + 1] = f2bf_bits(v.y);
    xb[i4 + 2] = f2bf_bits(v.z); xb[i4 + 3] = f2bf_bits(v.w);
  }
}

// ---------- degree / CSR ----------
__global__ void k_zero_int(int* p, int n) {
  int i = blockIdx.x * 256 + threadIdx.x;
  if (i < n) p[i] = 0;
}
__global__ void k_count(const int* ecol, int* cnt) {
  int e = blockIdx.x * 256 + threadIdx.x;
  if (e < NE) atomicAdd(&cnt[ecol[e]], 1);
}
__global__ void k_dinv(const int* cnt, float* dinv) {
  int i = blockIdx.x * 256 + threadIdx.x;
  if (i < NN) dinv[i] = rsqrtf((float)(cnt[i] + 1));   // +1 self loop
}
__global__ void k_scan1(const int* cnt, int* indptr, int* bsum, int n) {
  __shared__ int sm[256];
  int tid = threadIdx.x;
  int i = blockIdx.x * 256 + tid;
  int v = (i < n) ? cnt[i] : 0;
  sm[tid] = v;
  __syncthreads();
  for (int off = 1; off < 256; off <<= 1) {
    int t = (tid >= off) ? sm[tid - off] : 0;
    __syncthreads();
    sm[tid] += t;
    __syncthreads();
  }
  if (i < n) indptr[i] = sm[tid] - v;
  if (tid == 255) bsum[blockIdx.x] = sm[255];
}
__global__ void k_scan2(int* bsum, int nb) {
  __shared__ int sm[256];
  int tid = threadIdx.x;
  int v = (tid < nb) ? bsum[tid] : 0;
  sm[tid] = v;
  __syncthreads();
  for (int off = 1; off < 256; off <<= 1) {
    int t = (tid >= off) ? sm[tid - off] : 0;
    __syncthreads();
    sm[tid] += t;
    __syncthreads();
  }
  if (tid < nb) bsum[tid] = sm[tid] - v;
  if (tid == 0) bsum[nb] = sm[255];
}
__global__ void k_scan3(int* indptr, const int* bsum, int n, int nb) {
  int i = blockIdx.x * 256 + threadIdx.x;
  if (i < n) indptr[i] += bsum[i >> 8];
  else if (i == n) indptr[n] = bsum[nb];
}
__global__ void k_fill(const int* erow, const int* ecol, const int* indptr,
                       int* fill, int* srcs) {
  int e = blockIdx.x * 256 + threadIdx.x;
  if (e >= NE) return;
  int c = ecol[e];
  int p = indptr[c] + atomicAdd(&fill[c], 1);
  srcs[p] = erow[e];
}

// ---------- BN folding:  bn(h)@W = h@W' + c ----------
// Wtb[j][k] = bf16( s[k] * W[k][j] )   (transposed for MFMA B-fragment reads)
__global__ void k_prep_wt(const void* W, const void* g, const void* rv,
                          unsigned short* Wtb, int K, int NOUT, const int* flags) {
  int idx = blockIdx.x * 256 + threadIdx.x;
  if (idx >= K * NOUT) return;
  int isbf = flags[0];
  int j = idx / K, k = idx % K;
  float s = loadf(g, k, isbf) * rsqrtf(loadf(rv, k, isbf) + 1e-5f);
  Wtb[idx] = f2bf_bits(s * loadf(W, (size_t)k * NOUT + j, isbf));
}
// one block (64 lanes) per output column j
__global__ void k_prep_c(const void* W, const void* g, const void* b,
                         const void* rm, const void* rv, float* cvec,
                         int K, int NOUT, const int* flags) {
  int j = blockIdx.x;
  int lane = threadIdx.x;
  int isbf = flags[0];
  float acc = 0.f;
  for (int k = lane; k < K; k += 64) {
    float s = loadf(g, k, isbf) * rsqrtf(loadf(rv, k, isbf) + 1e-5f);
    float t = loadf(b, k, isbf) - loadf(rm, k, isbf) * s;
    acc += t * loadf(W, (size_t)k * NOUT + j, isbf);
  }
#pragma unroll
  for (int off = 32; off; off >>= 1) acc += __shfl_down(acc, off);
  if (lane == 0) cvec[j] = acc;
}

// ---------- MFMA GEMM: hb[i][j] = bf16( dinv[i]*( h[i,:] @ W'[:,j] + c[j] ) ) ----
// 4 waves/block, 16 rows/wave, 64 rows/block. A direct from global (bf16 rows,
// 128 per region), B from Wtb[NOUT][K] (L2-resident), fp32 MFMA accumulate.
// mfma_f32_16x16x32_bf16 layouts: A row=l&15,k=8*(l>>4)+j ; B col=l&15,same k;
// D col=l&15,row=(l>>4)*4+reg  [m89-verified].
template <int NOUT, int K>
__global__ __launch_bounds__(256) void k_gemm_mfma(
    const unsigned short* __restrict__ h0, const unsigned short* __restrict__ h1,
    const unsigned short* __restrict__ h2, const unsigned short* __restrict__ Wtb,
    const float* __restrict__ cvec, const float* __restrict__ dinv,
    unsigned short* __restrict__ hb) {
  constexpr int KS = K / 32;
  constexpr int NT = NOUT / 16;
  int tid = threadIdx.x;
  int wv = tid >> 6, lane = tid & 63;
  int row0 = blockIdx.x * 64 + wv * 16;
  int l15 = lane & 15;
  int kq = lane >> 4;               // 0..3
  int arow = row0 + l15;
  bool inb = arow < NN;

  bf16x8 afrag[KS];
#pragma unroll
  for (int ks = 0; ks < KS; ++ks) {
    int kg = ks * 32 + kq * 8;      // never straddles a 128-region
    const unsigned short* src = (kg >> 7) == 0 ? h0 : ((kg >> 7) == 1 ? h1 : h2);
    ushort8 u = (ushort8)0;
    if (inb) u = *reinterpret_cast<const ushort8*>(src + (size_t)arow * 128 + (kg & 127));
    afrag[ks] = __builtin_bit_cast(bf16x8, u);
  }

  f32x4 acc[NT];
#pragma unroll
  for (int nt = 0; nt < NT; ++nt) acc[nt] = (f32x4)0.f;

#pragma unroll
  for (int nt = 0; nt < NT; ++nt) {
    const unsigned short* wrow = Wtb + (size_t)(nt * 16 + l15) * K + kq * 8;
#pragma unroll
    for (int ks = 0; ks < KS; ++ks) {
      ushort8 u = *reinterpret_cast<const ushort8*>(wrow + ks * 32);
      acc[nt] = __builtin_amdgcn_mfma_f32_16x16x32_bf16(
          afrag[ks], __builtin_bit_cast(bf16x8, u), acc[nt], 0, 0, 0);
    }
  }

  // epilogue: D row = (lane>>4)*4 + reg, col = lane&15 (+16*nt)
  int orow0 = row0 + kq * 4;
  float dv[4];
  bool ob[4];
#pragma unroll
  for (int r = 0; r < 4; ++r) {
    int orow = orow0 + r;
    ob[r] = orow < NN;
    dv[r] = ob[r] ? dinv[orow] : 0.f;
  }
#pragma unroll
  for (int nt = 0; nt < NT; ++nt) {
    int col = nt * 16 + l15;
    float cv = cvec[col];
#pragma unroll
    for (int r = 0; r < 4; ++r) {
      if (ob[r])
        hb[(size_t)(orow0 + r) * NOUT + col] = f2bf_bits(dv[r] * (acc[nt][r] + cv));
    }
  }
}

// ---------- aggregation: one wave per node, bf16 gather from CSR ----------
template <int DPL, bool RELU>
__global__ __launch_bounds__(256) void k_agg(
    const unsigned short* __restrict__ hb, const int* __restrict__ indptr,
    const int* __restrict__ srcs, const float* __restrict__ dinv,
    const void* __restrict__ bias, void* __restrict__ dout, size_t region_off,
    unsigned short* __restrict__ rb, const int* __restrict__ flags) {
  constexpr int NOUT = DPL * 64;
  int gw = (blockIdx.x * 256 + threadIdx.x) >> 6;
  int lane = threadIdx.x & 63;
  if (gw >= NN) return;
  int isbf = flags[0];
  int e0 = indptr[gw], e1 = indptr[gw + 1];
  int e = e0;
  float o0, o1;
  if constexpr (DPL == 2) {
    unsigned int v = *reinterpret_cast<const unsigned int*>(
        hb + (size_t)gw * NOUT + lane * 2);
    float s00 = bf2f_bits((unsigned short)v), s01 = bf2f_bits((unsigned short)(v >> 16));
    float s10 = 0.f, s11 = 0.f, s20 = 0.f, s21 = 0.f, s30 = 0.f, s31 = 0.f;
    for (; e + 3 < e1; e += 4) {
      int a = srcs[e], b = srcs[e + 1], c = srcs[e + 2], d = srcs[e + 3];
      unsigned int v0 = *reinterpret_cast<const unsigned int*>(hb + (size_t)a * NOUT + lane * 2);
      unsigned int v1 = *reinterpret_cast<const unsigned int*>(hb + (size_t)b * NOUT + lane * 2);
      unsigned int v2 = *reinterpret_cast<const unsigned int*>(hb + (size_t)c * NOUT + lane * 2);
      unsigned int v3 = *reinterpret_cast<const unsigned int*>(hb + (size_t)d * NOUT + lane * 2);
      s00 += bf2f_bits((unsigned short)v0); s01 += bf2f_bits((unsigned short)(v0 >> 16));
      s10 += bf2f_bits((unsigned short)v1); s11 += bf2f_bits((unsigned short)(v1 >> 16));
      s20 += bf2f_bits((unsigned short)v2); s21 += bf2f_bits((unsigned short)(v2 >> 16));
      s30 += bf2f_bits((unsigned short)v3); s31 += bf2f_bits((unsigned short)(v3 >> 16));
    }
    for (; e < e1; ++e) {
      int a = srcs[e];
      unsigned int v0 = *reinterpret_cast<const unsigned int*>(hb + (size_t)a * NOUT + lane * 2);
      s00 += bf2f_bits((unsigned short)v0); s01 += bf2f_bits((unsigned short)(v0 >> 16));
    }
    float dv = dinv[gw];
    o0 = dv * ((s00 + s10) + (s20 + s30)) + loadf(bias, (size_t)(lane * 2 + 0), isbf);
    o1 = dv * ((s01 + s11) + (s21 + s31)) + loadf(bias, (size_t)(lane * 2 + 1), isbf);
    if (RELU) { o0 = fmaxf(o0, 0.f); o1 = fmaxf(o1, 0.f); }
    size_t eo = region_off + (size_t)gw * NOUT + lane * 2;
    if (isbf) {
      unsigned int pk = (unsigned int)f2bf_bits(o0) | ((unsigned int)f2bf_bits(o1) << 16);
      *reinterpret_cast<unsigned int*>((unsigned short*)dout + eo) = pk;
    } else {
      float2 fo; fo.x = o0; fo.y = o1;
      *reinterpret_cast<float2*>((float*)dout + eo) = fo;
    }
    if (rb) {
      unsigned int pk = (unsigned int)f2bf_bits(o0) | ((unsigned int)f2bf_bits(o1) << 16);
      *reinterpret_cast<unsigned int*>(rb + (size_t)gw * NOUT + lane * 2) = pk;
    }
  } else {
    float s0 = bf2f_bits(hb[(size_t)gw * NOUT + lane]);
    float s1 = 0.f, s2 = 0.f, s3 = 0.f;
    for (; e + 3 < e1; e += 4) {
      int a = srcs[e], b = srcs[e + 1], c = srcs[e + 2], d = srcs[e + 3];
      s0 += bf2f_bits(hb[(size_t)a * NOUT + lane]);
      s1 += bf2f_bits(hb[(size_t)b * NOUT + lane]);
      s2 += bf2f_bits(hb[(size_t)c * NOUT + lane]);
      s3 += bf2f_bits(hb[(size_t)d * NOUT + lane]);
    }
    for (; e < e1; ++e) s0 += bf2f_bits(hb[(size_t)srcs[e] * NOUT + lane]);
    float dv = dinv[gw];
    o0 = dv * ((s0 + s1) + (s2 + s3)) + loadf(bias, (size_t)lane, isbf);
    if (RELU) o0 = fmaxf(o0, 0.f);
    size_t eo = region_off + (size_t)gw * NOUT + lane;
    if (isbf) ((unsigned short*)dout)[eo] = f2bf_bits(o0);
    else      ((float*)dout)[eo] = o0;
    if (rb) rb[(size_t)gw * NOUT + lane] = f2bf_bits(o0);
  }
}

extern "C" void kernel_launch(void* const* d_in, const int* in_sizes, int n_in,
                              void* d_out, int out_size, void* d_ws, size_t ws_size,
                              hipStream_t stream) {
  const void* x    = d_in[0];
  const void* ei   = d_in[1];
  const void* W1   = d_in[4];
  const void* b1   = d_in[5];
  const void* Wc0  = d_in[6];
  const void* bc0  = d_in[7];
  const void* Wc1  = d_in[8];
  const void* bc1  = d_in[9];
  const void* Wout = d_in[10];
  const void* bout = d_in[11];
  const void *bn1g = d_in[12], *bn1b = d_in[13], *bn1rm = d_in[14], *bn1rv = d_in[15];
  const void *bc0g = d_in[16], *bc0b = d_in[17], *bc0rm = d_in[18], *bc0rv = d_in[19];
  const void *bc1g = d_in[20], *bc1b = d_in[21], *bc1rm = d_in[22], *bc1rv = d_in[23];
  const void *bn2g = d_in[24], *bn2b = d_in[25], *bn2rm = d_in[26], *bn2rv = d_in[27];
  (void)in_sizes; (void)n_in; (void)out_size; (void)ws_size;

  char* w = (char*)d_ws;
  auto carve = [&](size_t bytes) {
    char* p = w;
    w += (bytes + 255) & ~(size_t)255;
    return p;
  };
  int*   flags  = (int*)  carve(256);
  float* dinv   = (float*)carve(sizeof(float) * NN);
  int*   cnt    = (int*)  carve(sizeof(int) * NN);
  int*   fill   = (int*)  carve(sizeof(int) * NN);
  int*   indptr = (int*)  carve(sizeof(int) * (NN + 1));
  int*   bsum   = (int*)  carve(sizeof(int) * 256);
  int*   erow   = (int*)  carve(sizeof(int) * NE);
  int*   ecol   = (int*)  carve(sizeof(int) * NE);
  int*   srcs   = (int*)  carve(sizeof(int) * NE);
  unsigned short* Wtb = (unsigned short*)carve(sizeof(short) * 384 * 128);
  float* cvec   = (float*)carve(sizeof(float) * 128);
  unsigned short* xb  = (unsigned short*)carve(sizeof(short) * (size_t)NN * 128);
  unsigned short* hb  = (unsigned short*)carve(sizeof(short) * (size_t)NN * 128);
  unsigned short* rb0 = (unsigned short*)carve(sizeof(short) * (size_t)NN * 128);
  unsigned short* rb1 = (unsigned short*)carve(sizeof(short) * (size_t)NN * 128);
  unsigned short* rb2 = (unsigned short*)carve(sizeof(short) * (size_t)NN * 128);

  const int gN  = (NN + 255) / 256;
  const int gE  = (NE + 255) / 256;
  const int nb  = (NN + 255) / 256;
  const int gG  = (NN + 63) / 64;       // 782 MFMA gemm blocks
  const int gA  = (NN + 3) / 4;

  k_sniff<<<1, 256, 0, stream>>>(x, ei, flags);
  k_cvt_edges<<<gE, 256, 0, stream>>>(ei, erow, ecol, flags);
  k_cvt_xb<<<(NN * 128 / 4 + 255) / 256, 256, 0, stream>>>(x, xb, flags);
  k_zero_int<<<gN, 256, 0, stream>>>(cnt, NN);
  k_zero_int<<<gN, 256, 0, stream>>>(fill, NN);
  k_count<<<gE, 256, 0, stream>>>(ecol, cnt);
  k_dinv<<<gN, 256, 0, stream>>>(cnt, dinv);
  k_scan1<<<nb, 256, 0, stream>>>(cnt, indptr, bsum, NN);
  k_scan2<<<1, 256, 0, stream>>>(bsum, nb);
  k_scan3<<<(NN + 1 + 255) / 256, 256, 0, stream>>>(indptr, bsum, NN, nb);
  k_fill<<<gE, 256, 0, stream>>>(erow, ecol, indptr, fill, srcs);

  const size_t offO  = 0;
  const size_t offR0 = (size_t)NN * 64;
  const size_t offR1 = offR0 + (size_t)NN * 128;
  const size_t offR2 = offR1 + (size_t)NN * 128;

  // L1: bn1 + W1 (128->128), relu -> r0
  k_prep_wt<<<(128 * 128 + 255) / 256, 256, 0, stream>>>(W1, bn1g, bn1rv, Wtb, 128, 128, flags);
  k_prep_c<<<128, 64, 0, stream>>>(W1, bn1g, bn1b, bn1rm, bn1rv, cvec, 128, 128, flags);
  k_gemm_mfma<128, 128><<<gG, 256, 0, stream>>>(xb, nullptr, nullptr, Wtb, cvec, dinv, hb);
  k_agg<2, true><<<gA, 256, 0, stream>>>(hb, indptr, srcs, dinv, b1, d_out, offR0, rb0, flags);

  // L2: bnc0 + Wc0 (128->128), relu -> r1
  k_prep_wt<<<(128 * 128 + 255) / 256, 256, 0, stream>>>(Wc0, bc0g, bc0rv, Wtb, 128, 128, flags);
  k_prep_c<<<128, 64, 0, stream>>>(Wc0, bc0g, bc0b, bc0rm, bc0rv, cvec, 128, 128, flags);
  k_gemm_mfma<128, 128><<<gG, 256, 0, stream>>>(rb0, nullptr, nullptr, Wtb, cvec, dinv, hb);
  k_agg<2, true><<<gA, 256, 0, stream>>>(hb, indptr, srcs, dinv, bc0, d_out, offR1, rb1, flags);

  // L3: bnc1 + Wc1 (256->128) on concat(r0,r1), relu -> r2
  k_prep_wt<<<(256 * 128 + 255) / 256, 256, 0, stream>>>(Wc1, bc1g, bc1rv, Wtb, 256, 128, flags);
  k_prep_c<<<128, 64, 0, stream>>>(Wc1, bc1g, bc1b, bc1rm, bc1rv, cvec, 256, 128, flags);
  k_gemm_mfma<128, 256><<<gG, 256, 0, stream>>>(rb0, rb1, nullptr, Wtb, cvec, dinv, hb);
  k_agg<2, true><<<gA, 256, 0, stream>>>(hb, indptr, srcs, dinv, bc1, d_out, offR2, rb2, flags);

  // L4: bn2 + Wout (384->64) on concat(r0,r1,r2), no relu -> out
  k_prep_wt<<<(384 * 64 + 255) / 256, 256, 0, stream>>>(Wout, bn2g, bn2rv, Wtb, 384, 64, flags);
  k_prep_c<<<64, 64, 0, stream>>>(Wout, bn2g, bn2b, bn2rm, bn2rv, cvec, 384, 64, flags);
  k_gemm_mfma<64, 384><<<gG, 256, 0, stream>>>(rb0, rb1, rb2, Wtb, cvec, dinv, hb);
  k_agg<1, false><<<gA, 256, 0, stream>>>(hb, indptr, srcs, dinv, bout, d_out, offO, nullptr, flags);
}

// Round 5
// 357.726 us; speedup vs baseline: 2.8240x; 1.2078x over previous
//
#include <hip/hip_runtime.h>
#include <hip/hip_bf16.h>
#include <stdint.h>

#define NN 50000
#define NE 800000

typedef unsigned short ushort8 __attribute__((ext_vector_type(8)));
typedef __bf16 bf16x8 __attribute__((ext_vector_type(8)));
typedef float f32x4 __attribute__((ext_vector_type(4)));

// ---------- dtype helpers ----------
__device__ __forceinline__ float bf2f_bits(unsigned short u) {
  unsigned int x = ((unsigned int)u) << 16;
  float f;
  __builtin_memcpy(&f, &x, 4);
  return f;
}
__device__ __forceinline__ unsigned short f2bf_bits(float f) {
  unsigned int x;
  __builtin_memcpy(&x, &f, 4);
  unsigned int lsb = (x >> 16) & 1u;
  x += 0x7fffu + lsb;                       // round to nearest even
  return (unsigned short)(x >> 16);
}
__device__ __forceinline__ float loadf(const void* base, size_t idx, int isbf) {
  if (isbf) return bf2f_bits(((const unsigned short*)base)[idx]);
  return ((const float*)base)[idx];
}

// ---------- dtype sniffing (deterministic, graph-safe) ----------
__global__ void k_sniff(const void* x, const void* ei, int* flags) {
  __shared__ int badbf;
  __shared__ int zodd;
  int tid = threadIdx.x;
  if (tid == 0) { badbf = 0; zodd = 0; }
  __syncthreads();
  unsigned short u = ((const unsigned short*)x)[tid];
  float v = bf2f_bits(u);
  float av = fabsf(v);
  int ok = (av == 0.0f) || (av > 1e-8f && av < 1e8f);
  if (!ok) atomicAdd(&badbf, 1);
  int e32 = ((const int*)ei)[tid];
  if ((tid & 1) && e32 == 0) atomicAdd(&zodd, 1);
  __syncthreads();
  if (tid == 0) {
    flags[0] = (badbf <= 12) ? 1 : 0;
    flags[1] = (zodd >= 100) ? 1 : 0;
  }
}

// convert edges + degree-count + per-edge rank in ONE atomic pass
__global__ void k_cvt_edges(const void* ei, int* erow, int* ecol, int* rank,
                            int* cnt, const int* flags) {
  int e = blockIdx.x * 256 + threadIdx.x;
  if (e >= NE) return;
  int r, c;
  if (flags[1]) {
    const long long* p = (const long long*)ei;
    r = (int)p[e];
    c = (int)p[NE + e];
  } else {
    const int* p = (const int*)ei;
    r = p[e];
    c = p[NE + e];
  }
  erow[e] = r;
  ecol[e] = c;
  rank[e] = atomicAdd(&cnt[c], 1);
}

// x (fp32 or bf16) -> bf16 internal, 4 elems/thread
__global__ void k_cvt_xb(const void* x, unsigned short* xb, const int* flags) {
  int i4 = (blockIdx.x * 256 + threadIdx.x) * 4;
  if (i4 >= NN * 128) return;
  int isbf = flags[0];
  if (isbf) {
    *reinterpret_cast<uint2*>(xb + i4) =
        *reinterpret_cast<const uint2*>((const unsigned short*)x + i4);
  } else {
    float4 v = *reinterpret_cast<const float4*>((const float*)x + i4);
    xb[i4 + 0] = f2bf_bits(v.x); xb[i4 + 1] = f2bf_bits(v.y);
    xb[i4 + 2] = f2bf_bits(v.z); xb[i4 + 3] = f2bf_bits(v.w);
  }
}

// ---------- degree / CSR ----------
__global__ void k_zero_int(int* p, int n) {
  int i = blockIdx.x * 256 + threadIdx.x;
  if (i < n) p[i] = 0;
}
__global__ void k_dinv(const int* cnt, float* dinv) {
  int i = blockIdx.x * 256 + threadIdx.x;
  if (i < NN) dinv[i] = rsqrtf((float)(cnt[i] + 1));   // +1 self loop
}
__global__ void k_scan1(const int* cnt, int* indptr, int* bsum, int n) {
  __shared__ int sm[256];
  int tid = threadIdx.x;
  int i = blockIdx.x * 256 + tid;
  int v = (i < n) ? cnt[i] : 0;
  sm[tid] = v;
  __syncthreads();
  for (int off = 1; off < 256; off <<= 1) {
    int t = (tid >= off) ? sm[tid - off] : 0;
    __syncthreads();
    sm[tid] += t;
    __syncthreads();
  }
  if (i < n) indptr[i] = sm[tid] - v;
  if (tid == 255) bsum[blockIdx.x] = sm[255];
}
__global__ void k_scan2(int* bsum, int nb) {
  __shared__ int sm[256];
  int tid = threadIdx.x;
  int v = (tid < nb) ? bsum[tid] : 0;
  sm[tid] = v;
  __syncthreads();
  for (int off = 1; off < 256; off <<= 1) {
    int t = (tid >= off) ? sm[tid - off] : 0;
    __syncthreads();
    sm[tid] += t;
    __syncthreads();
  }
  if (tid < nb) bsum[tid] = sm[tid] - v;
  if (tid == 0) bsum[nb] = sm[255];
}
__global__ void k_scan3(int* indptr, const int* bsum, int n, int nb) {
  int i = blockIdx.x * 256 + threadIdx.x;
  if (i < n) indptr[i] += bsum[i >> 8];
  else if (i == n) indptr[n] = bsum[nb];
}
// atomic-free fill: slot precomputed from rank
__global__ void k_fill(const int* erow, const int* ecol, const int* rank,
                       const int* indptr, int* srcs) {
  int e = blockIdx.x * 256 + threadIdx.x;
  if (e >= NE) return;
  srcs[indptr[ecol[e]] + rank[e]] = erow[e];
}

// ---------- BN folding:  bn(h)@W = h@W' + c ----------
__global__ void k_prep_wt(const void* W, const void* g, const void* rv,
                          unsigned short* Wtb, int K, int NOUT, const int* flags) {
  int idx = blockIdx.x * 256 + threadIdx.x;
  if (idx >= K * NOUT) return;
  int isbf = flags[0];
  int j = idx / K, k = idx % K;
  float s = loadf(g, k, isbf) * rsqrtf(loadf(rv, k, isbf) + 1e-5f);
  Wtb[idx] = f2bf_bits(s * loadf(W, (size_t)k * NOUT + j, isbf));
}
__global__ void k_prep_c(const void* W, const void* g, const void* b,
                         const void* rm, const void* rv, float* cvec,
                         int K, int NOUT, const int* flags) {
  int j = blockIdx.x;
  int lane = threadIdx.x;
  int isbf = flags[0];
  float acc = 0.f;
  for (int k = lane; k < K; k += 64) {
    float s = loadf(g, k, isbf) * rsqrtf(loadf(rv, k, isbf) + 1e-5f);
    float t = loadf(b, k, isbf) - loadf(rm, k, isbf) * s;
    acc += t * loadf(W, (size_t)k * NOUT + j, isbf);
  }
#pragma unroll
  for (int off = 32; off; off >>= 1) acc += __shfl_down(acc, off);
  if (lane == 0) cvec[j] = acc;
}

// ---------- MFMA GEMM (unchanged from R4) ----------
template <int NOUT, int K>
__global__ __launch_bounds__(256) void k_gemm_mfma(
    const unsigned short* __restrict__ h0, const unsigned short* __restrict__ h1,
    const unsigned short* __restrict__ h2, const unsigned short* __restrict__ Wtb,
    const float* __restrict__ cvec, const float* __restrict__ dinv,
    unsigned short* __restrict__ hb) {
  constexpr int KS = K / 32;
  constexpr int NT = NOUT / 16;
  int tid = threadIdx.x;
  int wv = tid >> 6, lane = tid & 63;
  int row0 = blockIdx.x * 64 + wv * 16;
  int l15 = lane & 15;
  int kq = lane >> 4;
  int arow = row0 + l15;
  bool inb = arow < NN;

  bf16x8 afrag[KS];
#pragma unroll
  for (int ks = 0; ks < KS; ++ks) {
    int kg = ks * 32 + kq * 8;
    const unsigned short* src = (kg >> 7) == 0 ? h0 : ((kg >> 7) == 1 ? h1 : h2);
    ushort8 u = (ushort8)0;
    if (inb) u = *reinterpret_cast<const ushort8*>(src + (size_t)arow * 128 + (kg & 127));
    afrag[ks] = __builtin_bit_cast(bf16x8, u);
  }

  f32x4 acc[NT];
#pragma unroll
  for (int nt = 0; nt < NT; ++nt) acc[nt] = (f32x4)0.f;

#pragma unroll
  for (int nt = 0; nt < NT; ++nt) {
    const unsigned short* wrow = Wtb + (size_t)(nt * 16 + l15) * K + kq * 8;
#pragma unroll
    for (int ks = 0; ks < KS; ++ks) {
      ushort8 u = *reinterpret_cast<const ushort8*>(wrow + ks * 32);
      acc[nt] = __builtin_amdgcn_mfma_f32_16x16x32_bf16(
          afrag[ks], __builtin_bit_cast(bf16x8, u), acc[nt], 0, 0, 0);
    }
  }

  int orow0 = row0 + kq * 4;
  float dv[4];
  bool ob[4];
#pragma unroll
  for (int r = 0; r < 4; ++r) {
    int orow = orow0 + r;
    ob[r] = orow < NN;
    dv[r] = ob[r] ? dinv[orow] : 0.f;
  }
#pragma unroll
  for (int nt = 0; nt < NT; ++nt) {
    int col = nt * 16 + l15;
    float cv = cvec[col];
#pragma unroll
    for (int r = 0; r < 4; ++r) {
      if (ob[r])
        hb[(size_t)(orow0 + r) * NOUT + col] = f2bf_bits(dv[r] * (acc[nt][r] + cv));
    }
  }
}

// ---------- aggregation: 32 lanes/node, 2 nodes/wave, uint2 gathers ----------
template <int DPL, bool RELU>
__global__ __launch_bounds__(256) void k_agg(
    const unsigned short* __restrict__ hb, const int* __restrict__ indptr,
    const int* __restrict__ srcs, const float* __restrict__ dinv,
    const void* __restrict__ bias, void* __restrict__ dout, size_t region_off,
    unsigned short* __restrict__ rb, const int* __restrict__ flags) {
  constexpr int NOUT = DPL * 64;            // 128 (DPL2) or 64 (DPL1)
  int gw = blockIdx.x * 8 + (threadIdx.x >> 5);   // node (8 half-waves/block)
  int lane = threadIdx.x & 31;
  if (gw >= NN) return;
  int isbf = flags[0];
  int e0 = indptr[gw], e1 = indptr[gw + 1];
  int e = e0;
  float dv = dinv[gw];

  if constexpr (DPL == 2) {
    // lane covers features [4*lane .. 4*lane+3] via one uint2 (8B) per row
    size_t co = (size_t)lane * 4;
    uint2 sv = *reinterpret_cast<const uint2*>(hb + (size_t)gw * 128 + co);
    float a0 = bf2f_bits((unsigned short)sv.x), a1 = bf2f_bits((unsigned short)(sv.x >> 16));
    float a2 = bf2f_bits((unsigned short)sv.y), a3 = bf2f_bits((unsigned short)(sv.y >> 16));
    float b0 = 0.f, b1 = 0.f, b2 = 0.f, b3 = 0.f;
    float c0 = 0.f, c1 = 0.f, c2 = 0.f, c3 = 0.f;
    float d0 = 0.f, d1 = 0.f, d2 = 0.f, d3 = 0.f;
    for (; e + 3 < e1; e += 4) {
      int sa = srcs[e], sb = srcs[e + 1], sc = srcs[e + 2], sd = srcs[e + 3];
      uint2 va = *reinterpret_cast<const uint2*>(hb + (size_t)sa * 128 + co);
      uint2 vb = *reinterpret_cast<const uint2*>(hb + (size_t)sb * 128 + co);
      uint2 vc = *reinterpret_cast<const uint2*>(hb + (size_t)sc * 128 + co);
      uint2 vd = *reinterpret_cast<const uint2*>(hb + (size_t)sd * 128 + co);
      a0 += bf2f_bits((unsigned short)va.x); a1 += bf2f_bits((unsigned short)(va.x >> 16));
      a2 += bf2f_bits((unsigned short)va.y); a3 += bf2f_bits((unsigned short)(va.y >> 16));
      b0 += bf2f_bits((unsigned short)vb.x); b1 += bf2f_bits((unsigned short)(vb.x >> 16));
      b2 += bf2f_bits((unsigned short)vb.y); b3 += bf2f_bits((unsigned short)(vb.y >> 16));
      c0 += bf2f_bits((unsigned short)vc.x); c1 += bf2f_bits((unsigned short)(vc.x >> 16));
      c2 += bf2f_bits((unsigned short)vc.y); c3 += bf2f_bits((unsigned short)(vc.y >> 16));
      d0 += bf2f_bits((unsigned short)vd.x); d1 += bf2f_bits((unsigned short)(vd.x >> 16));
      d2 += bf2f_bits((unsigned short)vd.y); d3 += bf2f_bits((unsigned short)(vd.y >> 16));
    }
    for (; e < e1; ++e) {
      int sa = srcs[e];
      uint2 va = *reinterpret_cast<const uint2*>(hb + (size_t)sa * 128 + co);
      a0 += bf2f_bits((unsigned short)va.x); a1 += bf2f_bits((unsigned short)(va.x >> 16));
      a2 += bf2f_bits((unsigned short)va.y); a3 += bf2f_bits((unsigned short)(va.y >> 16));
    }
    float o0 = dv * ((a0 + b0) + (c0 + d0)) + loadf(bias, co + 0, isbf);
    float o1 = dv * ((a1 + b1) + (c1 + d1)) + loadf(bias, co + 1, isbf);
    float o2 = dv * ((a2 + b2) + (c2 + d2)) + loadf(bias, co + 2, isbf);
    float o3 = dv * ((a3 + b3) + (c3 + d3)) + loadf(bias, co + 3, isbf);
    if (RELU) {
      o0 = fmaxf(o0, 0.f); o1 = fmaxf(o1, 0.f);
      o2 = fmaxf(o2, 0.f); o3 = fmaxf(o3, 0.f);
    }
    size_t eo = region_off + (size_t)gw * 128 + co;
    uint2 pk;
    pk.x = (unsigned int)f2bf_bits(o0) | ((unsigned int)f2bf_bits(o1) << 16);
    pk.y = (unsigned int)f2bf_bits(o2) | ((unsigned int)f2bf_bits(o3) << 16);
    if (isbf) {
      *reinterpret_cast<uint2*>((unsigned short*)dout + eo) = pk;
    } else {
      float4 fo; fo.x = o0; fo.y = o1; fo.z = o2; fo.w = o3;
      *reinterpret_cast<float4*>((float*)dout + eo) = fo;
    }
    if (rb) *reinterpret_cast<uint2*>(rb + (size_t)gw * 128 + co) = pk;
  } else {
    // lane covers features [2*lane, 2*lane+1] via one uint (4B) per row
    size_t co = (size_t)lane * 2;
    unsigned int sv = *reinterpret_cast<const unsigned int*>(hb + (size_t)gw * 64 + co);
    float a0 = bf2f_bits((unsigned short)sv), a1 = bf2f_bits((unsigned short)(sv >> 16));
    float b0 = 0.f, b1 = 0.f, c0 = 0.f, c1 = 0.f, d0 = 0.f, d1 = 0.f;
    for (; e + 3 < e1; e += 4) {
      int sa = srcs[e], sb = srcs[e + 1], sc = srcs[e + 2], sd = srcs[e + 3];
      unsigned int va = *reinterpret_cast<const unsigned int*>(hb + (size_t)sa * 64 + co);
      unsigned int vb = *reinterpret_cast<const unsigned int*>(hb + (size_t)sb * 64 + co);
      unsigned int vc = *reinterpret_cast<const unsigned int*>(hb + (size_t)sc * 64 + co);
      unsigned int vd = *reinterpret_cast<const unsigned int*>(hb + (size_t)sd * 64 + co);
      a0 += bf2f_bits((unsigned short)va); a1 += bf2f_bits((unsigned short)(va >> 16));
      b0 += bf2f_bits((unsigned short)vb); b1 += bf2f_bits((unsigned short)(vb >> 16));
      c0 += bf2f_bits((unsigned short)vc); c1 += bf2f_bits((unsigned short)(vc >> 16));
      d0 += bf2f_bits((unsigned short)vd); d1 += bf2f_bits((unsigned short)(vd >> 16));
    }
    for (; e < e1; ++e) {
      int sa = srcs[e];
      unsigned int va = *reinterpret_cast<const unsigned int*>(hb + (size_t)sa * 64 + co);
      a0 += bf2f_bits((unsigned short)va); a1 += bf2f_bits((unsigned short)(va >> 16));
    }
    float o0 = dv * ((a0 + b0) + (c0 + d0)) + loadf(bias, co + 0, isbf);
    float o1 = dv * ((a1 + b1) + (c1 + d1)) + loadf(bias, co + 1, isbf);
    if (RELU) { o0 = fmaxf(o0, 0.f); o1 = fmaxf(o1, 0.f); }
    size_t eo = region_off + (size_t)gw * 64 + co;
    if (isbf) {
      unsigned int pk = (unsigned int)f2bf_bits(o0) | ((unsigned int)f2bf_bits(o1) << 16);
      *reinterpret_cast<unsigned int*>((unsigned short*)dout + eo) = pk;
    } else {
      float2 fo; fo.x = o0; fo.y = o1;
      *reinterpret_cast<float2*>((float*)dout + eo) = fo;
    }
    if (rb) {
      unsigned int pk = (unsigned int)f2bf_bits(o0) | ((unsigned int)f2bf_bits(o1) << 16);
      *reinterpret_cast<unsigned int*>(rb + (size_t)gw * 64 + co) = pk;
    }
  }
}

extern "C" void kernel_launch(void* const* d_in, const int* in_sizes, int n_in,
                              void* d_out, int out_size, void* d_ws, size_t ws_size,
                              hipStream_t stream) {
  const void* x    = d_in[0];
  const void* ei   = d_in[1];
  const void* W1   = d_in[4];
  const void* b1   = d_in[5];
  const void* Wc0  = d_in[6];
  const void* bc0  = d_in[7];
  const void* Wc1  = d_in[8];
  const void* bc1  = d_in[9];
  const void* Wout = d_in[10];
  const void* bout = d_in[11];
  const void *bn1g = d_in[12], *bn1b = d_in[13], *bn1rm = d_in[14], *bn1rv = d_in[15];
  const void *bc0g = d_in[16], *bc0b = d_in[17], *bc0rm = d_in[18], *bc0rv = d_in[19];
  const void *bc1g = d_in[20], *bc1b = d_in[21], *bc1rm = d_in[22], *bc1rv = d_in[23];
  const void *bn2g = d_in[24], *bn2b = d_in[25], *bn2rm = d_in[26], *bn2rv = d_in[27];
  (void)in_sizes; (void)n_in; (void)out_size; (void)ws_size;

  char* w = (char*)d_ws;
  auto carve = [&](size_t bytes) {
    char* p = w;
    w += (bytes + 255) & ~(size_t)255;
    return p;
  };
  int*   flags  = (int*)  carve(256);
  float* dinv   = (float*)carve(sizeof(float) * NN);
  int*   cnt    = (int*)  carve(sizeof(int) * NN);
  int*   indptr = (int*)  carve(sizeof(int) * (NN + 1));
  int*   bsum   = (int*)  carve(sizeof(int) * 256);
  int*   erow   = (int*)  carve(sizeof(int) * NE);
  int*   ecol   = (int*)  carve(sizeof(int) * NE);
  int*   rank   = (int*)  carve(sizeof(int) * NE);
  int*   srcs   = (int*)  carve(sizeof(int) * NE);
  unsigned short* Wtb = (unsigned short*)carve(sizeof(short) * 384 * 128);
  float* cvec   = (float*)carve(sizeof(float) * 128);
  unsigned short* xb  = (unsigned short*)carve(sizeof(short) * (size_t)NN * 128);
  unsigned short* hb  = (unsigned short*)carve(sizeof(short) * (size_t)NN * 128);
  unsigned short* rb0 = (unsigned short*)carve(sizeof(short) * (size_t)NN * 128);
  unsigned short* rb1 = (unsigned short*)carve(sizeof(short) * (size_t)NN * 128);
  unsigned short* rb2 = (unsigned short*)carve(sizeof(short) * (size_t)NN * 128);

  const int gN  = (NN + 255) / 256;
  const int gE  = (NE + 255) / 256;
  const int nb  = (NN + 255) / 256;
  const int gG  = (NN + 63) / 64;
  const int gA  = (NN + 7) / 8;          // 8 nodes/block (half-wave each)

  k_sniff<<<1, 256, 0, stream>>>(x, ei, flags);
  k_zero_int<<<gN, 256, 0, stream>>>(cnt, NN);
  k_cvt_edges<<<gE, 256, 0, stream>>>(ei, erow, ecol, rank, cnt, flags);
  k_cvt_xb<<<(NN * 128 / 4 + 255) / 256, 256, 0, stream>>>(x, xb, flags);
  k_dinv<<<gN, 256, 0, stream>>>(cnt, dinv);
  k_scan1<<<nb, 256, 0, stream>>>(cnt, indptr, bsum, NN);
  k_scan2<<<1, 256, 0, stream>>>(bsum, nb);
  k_scan3<<<(NN + 1 + 255) / 256, 256, 0, stream>>>(indptr, bsum, NN, nb);
  k_fill<<<gE, 256, 0, stream>>>(erow, ecol, rank, indptr, srcs);

  const size_t offO  = 0;
  const size_t offR0 = (size_t)NN * 64;
  const size_t offR1 = offR0 + (size_t)NN * 128;
  const size_t offR2 = offR1 + (size_t)NN * 128;

  // L1: bn1 + W1 (128->128), relu -> r0
  k_prep_wt<<<(128 * 128 + 255) / 256, 256, 0, stream>>>(W1, bn1g, bn1rv, Wtb, 128, 128, flags);
  k_prep_c<<<128, 64, 0, stream>>>(W1, bn1g, bn1b, bn1rm, bn1rv, cvec, 128, 128, flags);
  k_gemm_mfma<128, 128><<<gG, 256, 0, stream>>>(xb, nullptr, nullptr, Wtb, cvec, dinv, hb);
  k_agg<2, true><<<gA, 256, 0, stream>>>(hb, indptr, srcs, dinv, b1, d_out, offR0, rb0, flags);

  // L2: bnc0 + Wc0 (128->128), relu -> r1
  k_prep_wt<<<(128 * 128 + 255) / 256, 256, 0, stream>>>(Wc0, bc0g, bc0rv, Wtb, 128, 128, flags);
  k_prep_c<<<128, 64, 0, stream>>>(Wc0, bc0g, bc0b, bc0rm, bc0rv, cvec, 128, 128, flags);
  k_gemm_mfma<128, 128><<<gG, 256, 0, stream>>>(rb0, nullptr, nullptr, Wtb, cvec, dinv, hb);
  k_agg<2, true><<<gA, 256, 0, stream>>>(hb, indptr, srcs, dinv, bc0, d_out, offR1, rb1, flags);

  // L3: bnc1 + Wc1 (256->128) on concat(r0,r1), relu -> r2
  k_prep_wt<<<(256 * 128 + 255) / 256, 256, 0, stream>>>(Wc1, bc1g, bc1rv, Wtb, 256, 128, flags);
  k_prep_c<<<128, 64, 0, stream>>>(Wc1, bc1g, bc1b, bc1rm, bc1rv, cvec, 256, 128, flags);
  k_gemm_mfma<128, 256><<<gG, 256, 0, stream>>>(rb0, rb1, nullptr, Wtb, cvec, dinv, hb);
  k_agg<2, true><<<gA, 256, 0, stream>>>(hb, indptr, srcs, dinv, bc1, d_out, offR2, rb2, flags);

  // L4: bn2 + Wout (384->64) on concat(r0,r1,r2), no relu -> out
  k_prep_wt<<<(384 * 64 + 255) / 256, 256, 0, stream>>>(Wout, bn2g, bn2rv, Wtb, 384, 64, flags);
  k_prep_c<<<64, 64, 0, stream>>>(Wout, bn2g, bn2b, bn2rm, bn2rv, cvec, 384, 64, flags);
  k_gemm_mfma<64, 384><<<gG, 256, 0, stream>>>(rb0, rb1, rb2, Wtb, cvec, dinv, hb);
  k_agg<1, false><<<gA, 256, 0, stream>>>(hb, indptr, srcs, dinv, bout, d_out, offO, nullptr, flags);
}